// Round 12
// baseline (250.864 us; speedup 1.0000x reference)
//
#include <hip/hip_runtime.h>
#include <hip/hip_bf16.h>

typedef __bf16 bf16x8 __attribute__((ext_vector_type(8)));
typedef _Float16 f16x8 __attribute__((ext_vector_type(8)));
typedef unsigned short u16x8 __attribute__((ext_vector_type(8)));
typedef float f32x4 __attribute__((ext_vector_type(4)));
using bf16 = __hip_bfloat16;

constexpr int Cdim = 512;   // channels
constexpr int Nsp  = 4096;  // d*h*w
constexpr int NB   = 2;     // batch
constexpr float SCALE = 0.04419417382415922f;  // 512^-0.5
constexpr int EPITCH = 132; // epilogue LDS pitch (elems) for k_gemm_nt

// async 16B global->LDS (m97 pattern). LDS dest must be wave-uniform base + lane*16.
#define GL2LDS(gaddr, laddr)                                                              \
    __builtin_amdgcn_global_load_lds((const __attribute__((address_space(1))) void*)(gaddr), \
                                     (__attribute__((address_space(3))) void*)(laddr), 16, 0, 0)

// stage one 8KB [64 rows][64 elems] bf16 subtile: 1 GL2LDS per thread (512 thd),
// linear LDS dest, XOR-pre-swizzled global source chunk (verified k_gemm_nt pattern).
#define STG1(dst, src, ld) { int _o = tid * 16, _r = _o >> 7, _c = ((_o >> 4) ^ _r) & 7;      \
    GL2LDS((const unsigned short*)(src) + (size_t)_r * (ld) + _c * 8,                          \
           (unsigned short*)(dst) + (_o >> 1)); }

// ---------------------------------------------------------------- weights fp32 -> bf16 + zero lsum + GN stats,
// one launch: blocks 0..255 cvt, 256 zero-lsum, 257..320 groupnorm stats (64 b*g blocks).
__global__ __launch_bounds__(256) void k_cvt_all(const float* __restrict__ wq, const float* __restrict__ wk,
                                                 const float* __restrict__ wv, const float* __restrict__ wo,
                                                 bf16* __restrict__ wqkb, bf16* __restrict__ wvb,
                                                 bf16* __restrict__ wob, float* __restrict__ lsum,
                                                 const float* __restrict__ x, float* __restrict__ stats) {
    __shared__ float rs[4], rs2[4];
    if (blockIdx.x >= 257) {  // groupnorm stats for bg = blockIdx.x - 257
        int bg = blockIdx.x - 257;  // 0..63
        const float4* p = (const float4*)(x + (size_t)bg * (16 * 4096));
        float s = 0.f, s2 = 0.f;
        for (int i = threadIdx.x; i < 16384; i += 256) {
            float4 v = p[i];
            s  += v.x + v.y + v.z + v.w;
            s2 += v.x * v.x + v.y * v.y + v.z * v.z + v.w * v.w;
        }
        #pragma unroll
        for (int off = 32; off; off >>= 1) { s += __shfl_xor(s, off); s2 += __shfl_xor(s2, off); }
        int w = threadIdx.x >> 6;
        if ((threadIdx.x & 63) == 0) { rs[w] = s; rs2[w] = s2; }
        __syncthreads();
        if (threadIdx.x == 0) {
            float S = rs[0] + rs[1] + rs[2] + rs[3];
            float S2 = rs2[0] + rs2[1] + rs2[2] + rs2[3];
            float mean = S * (1.f / 65536.f);
            float var  = S2 * (1.f / 65536.f) - mean * mean;
            stats[bg * 2]     = mean;
            stats[bg * 2 + 1] = rsqrtf(var + 1e-6f);
        }
        return;
    }
    if (blockIdx.x == 256) {  // zero 8192-float lsum
        #pragma unroll
        for (int j = 0; j < 8; ++j)
            ((float4*)lsum)[8 * threadIdx.x + j] = float4{0.f, 0.f, 0.f, 0.f};
        return;
    }
    int i = blockIdx.x * 256 + threadIdx.x;  // 65536 float4 groups per weight
    float4 q = ((const float4*)wq)[i];
    float4 k = ((const float4*)wk)[i];
    float4 v = ((const float4*)wv)[i];
    float4 o = ((const float4*)wo)[i];
    bf16* dq = wqkb + (size_t)i * 4;
    dq[0] = __float2bfloat16(q.x); dq[1] = __float2bfloat16(q.y);
    dq[2] = __float2bfloat16(q.z); dq[3] = __float2bfloat16(q.w);
    bf16* dk = wqkb + 262144 + (size_t)i * 4;
    dk[0] = __float2bfloat16(k.x); dk[1] = __float2bfloat16(k.y);
    dk[2] = __float2bfloat16(k.z); dk[3] = __float2bfloat16(k.w);
    bf16* dv = wvb + (size_t)i * 4;
    dv[0] = __float2bfloat16(v.x); dv[1] = __float2bfloat16(v.y);
    dv[2] = __float2bfloat16(v.z); dv[3] = __float2bfloat16(v.w);
    bf16* dw = wob + (size_t)i * 4;
    dw[0] = __float2bfloat16(o.x); dw[1] = __float2bfloat16(o.y);
    dw[2] = __float2bfloat16(o.z); dw[3] = __float2bfloat16(o.w);
}

// ---------------------------------------------------------------- groupnorm apply + transpose -> ht[b,n,c] bf16
__global__ __launch_bounds__(256) void k_gn_apply(const float* __restrict__ x, const float* __restrict__ stats,
                                                  const float* __restrict__ gamma, const float* __restrict__ beta,
                                                  bf16* __restrict__ ht) {
    int b = blockIdx.y;
    int n0 = blockIdx.x * 64;
    int tid = threadIdx.x;
    __shared__ float tile[64][65];
    int nn_l = tid & 63, cc0 = tid >> 6;
    int cc_w = tid & 63, nn0 = tid >> 6;
    for (int c0 = 0; c0 < Cdim; c0 += 64) {
        #pragma unroll
        for (int p = 0; p < 16; ++p) {
            int cc = p * 4 + cc0;
            tile[cc][nn_l] = x[(size_t)(b * Cdim + c0 + cc) * Nsp + n0 + nn_l];
        }
        __syncthreads();
        int c = c0 + cc_w, g = c >> 4;
        float mean = stats[(b * 32 + g) * 2];
        float rstd = stats[(b * 32 + g) * 2 + 1];
        float ga = gamma[c], be = beta[c];
        #pragma unroll
        for (int p = 0; p < 16; ++p) {
            int nn = p * 4 + nn0;
            float v = tile[cc_w][nn];
            ht[(size_t)(b * Nsp + n0 + nn) * Cdim + c] = __float2bfloat16((v - mean) * rstd * ga + be);
        }
        __syncthreads();
    }
}

// ---------------------------------------------------------------- MFMA dtype dispatch
template <int DT>
__device__ __forceinline__ f32x4 mma16(u16x8 a, u16x8 b, f32x4 c) {
    if constexpr (DT == 0)
        return __builtin_amdgcn_mfma_f32_16x16x32_bf16(__builtin_bit_cast(bf16x8, a),
                                                       __builtin_bit_cast(bf16x8, b), c, 0, 0, 0);
    else
        return __builtin_amdgcn_mfma_f32_16x16x32_f16(__builtin_bit_cast(f16x8, a),
                                                      __builtin_bit_cast(f16x8, b), c, 0, 0, 0);
}

// ---------------------------------------------------------------- NT GEMM (m97 structure) + XOR-swizzled LDS
// Used for QK-proj, V-proj, O-proj (proven round-0 config).
template <int BM, int DT, int OUTT, int BIAS, int RESID, int SPLITK, int EXPSUM>
__global__ __launch_bounds__(256) void k_gemm_nt(
    const void* __restrict__ Av, long long As, int lda,
    const void* __restrict__ Bv, long long Bs, int ldb,
    const float* __restrict__ bias, const float* __restrict__ bias2,
    const float* __restrict__ resid, long long Rs,
    float* __restrict__ lsum,
    void* __restrict__ outv, long long Os,
    int N, int K) {
    constexpr int MT = BM / 32;       // m-tiles per wave
    constexpr int SME_STAGE = (BM + 128) * 64;
    constexpr int SME_EPI   = BM * EPITCH;
    constexpr int SME = SME_STAGE > SME_EPI ? SME_STAGE : SME_EPI;
    const int bm = blockIdx.x, bn = blockIdx.y, zz = blockIdx.z;
    const int bt  = (SPLITK > 1) ? (zz % NB) : zz;
    const int ksl = (SPLITK > 1) ? (zz / NB) : 0;
    const int Kc = K / SPLITK;
    const int kbeg = ksl * Kc;
    const unsigned short* Ab = (const unsigned short*)Av + (size_t)bt * As;
    const unsigned short* Bb = (const unsigned short*)Bv + (size_t)bt * Bs;
    const int tid = threadIdx.x, lane = tid & 63, w = tid >> 6;
    const int quad = lane >> 4, l16 = lane & 15;
    const int wm = w >> 1, wn = w & 1;
    __shared__ __align__(16) unsigned short smem[SME];
    unsigned short (*Asub)[64] = (unsigned short(*)[64])smem;
    unsigned short (*Bsub)[64] = (unsigned short(*)[64])(smem + BM * 64);
    f32x4 zero4 = {0.f, 0.f, 0.f, 0.f};
    f32x4 acc[MT][4];
    #pragma unroll
    for (int i = 0; i < MT; ++i)
        #pragma unroll
        for (int j = 0; j < 4; ++j) acc[i][j] = zero4;
    const int row0 = bm * BM, col0 = bn * 128;
    const size_t ldab = (size_t)lda * 2, ldbb = (size_t)ldb * 2;
    const int lsw = (l16 & 7) * 8;  // fragment-read swizzle (elems)
    for (int k0 = kbeg; k0 < kbeg + Kc; k0 += 64) {
        const char* Abase = (const char*)Ab + (size_t)k0 * 2;
        const char* Bbase = (const char*)Bb + (size_t)k0 * 2;
        #pragma unroll
        for (int p = 0; p < BM / 32; ++p) {
            int o = p * 4096 + tid * 16;         // byte offset into A LDS tile
            int r = o >> 7;                      // row (128 B per row)
            int cs = ((o >> 4) ^ r) & 7;         // swizzled source chunk
            GL2LDS(Abase + (size_t)(row0 + r) * ldab + cs * 16, (char*)smem + o);
        }
        #pragma unroll
        for (int p = 0; p < 4; ++p) {
            int o = p * 4096 + tid * 16;
            int r = o >> 7;
            int cs = ((o >> 4) ^ r) & 7;
            GL2LDS(Bbase + (size_t)(col0 + r) * ldbb + cs * 16, (char*)smem + BM * 128 + o);
        }
        __syncthreads();
        #pragma unroll
        for (int ks = 0; ks < 2; ++ks) {
            u16x8 af[MT], bfr[4];
            #pragma unroll
            for (int t = 0; t < MT; ++t)
                af[t] = *(const u16x8*)&Asub[wm * (BM / 2) + t * 16 + l16][(ks * 32 + quad * 8) ^ lsw];
            #pragma unroll
            for (int t = 0; t < 4; ++t)
                bfr[t] = *(const u16x8*)&Bsub[wn * 64 + t * 16 + l16][(ks * 32 + quad * 8) ^ lsw];
            #pragma unroll
            for (int tm = 0; tm < MT; ++tm)
                #pragma unroll
                for (int tn = 0; tn < 4; ++tn) acc[tm][tn] = mma16<DT>(af[tm], bfr[tn], acc[tm][tn]);
        }
        __syncthreads();
    }

    if constexpr (OUTT == 2) {
        // scalar fp32 epilogue (final projection: bias + residual + fp32 out)
        #pragma unroll
        for (int tm = 0; tm < MT; ++tm)
            #pragma unroll
            for (int tn = 0; tn < 4; ++tn)
                #pragma unroll
                for (int r = 0; r < 4; ++r) {
                    int row = row0 + wm * (BM / 2) + tm * 16 + quad * 4 + r;
                    int col = col0 + wn * 64 + tn * 16 + l16;
                    float v = acc[tm][tn][r];
                    if constexpr (BIAS == 1) v += bias[row];
                    else if constexpr (BIAS == 2) v += bias[col];
                    if constexpr (RESID) v += resid[(size_t)bt * Rs + (size_t)row * N + col];
                    ((float*)outv)[(size_t)zz * Os + (size_t)row * N + col] = v;
                }
    } else {
        // ---- LDS-transpose epilogue (2-byte outputs) ----
        #pragma unroll
        for (int tn = 0; tn < 4; ++tn) {
            int colL = wn * 64 + tn * 16 + l16;
            float bc = 0.f;
            if constexpr (BIAS == 2) bc = bias[col0 + colL];
            else if constexpr (BIAS == 3) {
                int col = col0 + colL;
                bc = (col < 512) ? bias[col] : bias2[col - 512];
            }
            #pragma unroll
            for (int tm = 0; tm < MT; ++tm)
                #pragma unroll
                for (int r = 0; r < 4; ++r) {
                    int rowL = wm * (BM / 2) + tm * 16 + quad * 4 + r;
                    float v = acc[tm][tn][r];
                    if constexpr (BIAS == 1) v += bias[row0 + rowL];
                    else if constexpr (BIAS == 2) v += bc;
                    else if constexpr (BIAS == 3) {
                        int col = col0 + colL;
                        v = (col < 512) ? (v + bc) * SCALE : v + bc;
                    }
                    if constexpr (EXPSUM) v = __expf(v);
                    unsigned short hv;
                    if constexpr (OUTT == 1) { _Float16 h = (_Float16)v; hv = __builtin_bit_cast(unsigned short, h); }
                    else { bf16 h = __float2bfloat16(v); hv = __builtin_bit_cast(unsigned short, h); }
                    smem[rowL * EPITCH + colL] = hv;
                }
        }
        __syncthreads();
        // read phase: chunk = tid&15 (8 cols), rows (tid>>4)*(BM/16) + i; 16B coalesced stores
        const int cch = (tid & 15) * 8;
        const int rg  = (tid >> 4) * (BM / 16);
        #pragma unroll
        for (int i = 0; i < BM / 16; ++i) {
            int rowL = rg + i;
            u16x8 hv = *(const u16x8*)&smem[rowL * EPITCH + cch];
            *(u16x8*)((unsigned short*)outv + (size_t)zz * Os + (size_t)(row0 + rowL) * N + col0 + cch) = hv;
            if constexpr (EXPSUM) {
                float ps = 0.f;
                #pragma unroll
                for (int e = 0; e < 8; ++e) {
                    bf16 h = __builtin_bit_cast(bf16, hv[e]);
                    ps += __bfloat162float(h);
                }
                #pragma unroll
                for (int m = 1; m < 16; m <<= 1) ps += __shfl_xor(ps, m);
                if ((lane & 15) == 0) atomicAdd(lsum + (size_t)bt * Nsp + row0 + rowL, ps);
            }
        }
    }
}

// ---------------------------------------------------------------- fused attention v7: v4 with merged S phase
// v4 (verified twice, 96.6us): 5 barriers/tile, ~7250 cy/tile vs ~4700 cy LDS-read floor -> rendezvous-bound
// at 1 block/CU (8-wave lockstep). v7 glues S0+S1 into ONE phase (4 barriers/tile) with a re-derived ledger:
// per tile: S consumes A=K-lo,B=K-hi (+Qhi LDS), stages V0->C; PV0 consumes C=V0, stages V1->A + K0(t+1)->B
// (+exp/P midbar); PV1 consumes A=V1, stages K1(t+1)->C; rotate (A,B,C)<-(B,C,A).
// vmcnt ledger (4 loads/half): S entry Q=[Klo,Khi] -> WAIT(0) trivial (both staged >=1 phase ago);
// PV0 entry Q=[V0] -> WAIT(0) (staged at S start, ~1 S-cluster ago); PV1 entry Q=[V1,K0+1] -> WAIT(4).
// Every stage targets a slot whose readers drained before this phase's barrier. kb regs reused between
// S halves (no VGPR change; the 128-arch law from r9/r10 stands: NO persistent register additions).
__global__ __launch_bounds__(512, 2) void k_attn(const bf16* __restrict__ QKt_, const bf16* __restrict__ Vm_,
                                                 float* __restrict__ lsum, bf16* __restrict__ Opart_) {
    constexpr int NT = 32;
    const int bx = blockIdx.x, js = blockIdx.y, bt = blockIdx.z;
    const int i0 = bx * 64;
    const int jbase = js * 2048;
    const unsigned short* Qb = (const unsigned short*)QKt_ + (size_t)bt * ((size_t)Nsp * 1024);
    const unsigned short* Vb = (const unsigned short*)Vm_ + (size_t)bt * ((size_t)Nsp * Cdim);  // [c][j] ld 4096
    const int tid = threadIdx.x, lane = tid & 63, w = tid >> 6;
    const int quad = lane >> 4, l16 = lane & 15;
    const int wm = w >> 2, wn = w & 3;   // 2 m-waves x 4 n-waves
    const int lsw = (l16 & 7) * 8;
    __shared__ __align__(16) unsigned short smem[69632];   // ring 3x16384 | Qhi 16384 | P 4096 (139264 B)
    unsigned short* Qhi = smem + 49152;
    unsigned short* P_l = smem + 65536;

    auto stgK = [&](int jj, int dh, unsigned short* dst) {
        #pragma unroll
        for (int s = 0; s < 4; ++s)
            STG1(dst + s * 4096, Qb + (size_t)jj * 1024 + 512 + dh * 256 + s * 64, 1024);
    };
    auto stgV = [&](int jj, int ch, unsigned short* dst) {
        #pragma unroll
        for (int s = 0; s < 4; ++s)
            STG1(dst + s * 4096, Vb + (size_t)(ch * 256 + s * 64) * 4096 + jj, 4096);
    };

#define FRD(base, row, kc) (*(const u16x8*)&(base)[(row) * 64 + ((kc) ^ lsw)])
#define WAIT_BAR(N) \
    asm volatile("s_waitcnt vmcnt(" #N ")" ::: "memory"); \
    __builtin_amdgcn_s_barrier(); \
    __builtin_amdgcn_sched_barrier(0);

    f32x4 zero4 = {0.f, 0.f, 0.f, 0.f};
    f32x4 acc[2][8];
    #pragma unroll
    for (int m = 0; m < 2; ++m)
        #pragma unroll
        for (int n = 0; n < 8; ++n) acc[m][n] = zero4;
    float rsum[2][4] = {{0.f, 0.f, 0.f, 0.f}, {0.f, 0.f, 0.f, 0.f}};
    u16x8 pa[2][2];

    unsigned short* A = smem;            // tile-0: K-d0 slot
    unsigned short* B = smem + 16384;    // tile-0: K-d1 slot
    unsigned short* C = smem + 32768;    // tile-0: V-c0 slot (Q-lo temp in prologue)

    // ---- prologue: Q-lo -> C (temp), Q-hi -> Qhi, K0(0)->A, K1(0)->B ----
    #pragma unroll
    for (int s = 0; s < 4; ++s) STG1(C + s * 4096, Qb + (size_t)i0 * 1024 + s * 64, 1024);
    #pragma unroll
    for (int s = 0; s < 4; ++s) STG1(Qhi + s * 4096, Qb + (size_t)i0 * 1024 + 256 + s * 64, 1024);
    stgK(jbase, 0, A);
    stgK(jbase, 1, B);
    WAIT_BAR(8)                          // Q-lo/Q-hi landed; K halves may be in flight
    u16x8 qa[2][8];                      // Q-d-lo in registers (64 VGPR)
    #pragma unroll
    for (int m = 0; m < 2; ++m)
        #pragma unroll
        for (int ks = 0; ks < 8; ++ks)
            qa[m][ks] = FRD(C + (ks >> 1) * 4096, wm * 32 + m * 16 + l16, (ks & 1) * 32 + quad * 8);
    asm volatile("s_waitcnt lgkmcnt(0)" ::: "memory");
    __builtin_amdgcn_s_barrier();        // C free for V0(0)
    __builtin_amdgcn_sched_barrier(0);

    for (int t = 0; t < NT; ++t) {
        const int j0 = jbase + t * 64;
        const int j1 = j0 + 64;
        f32x4 aS[2] = {zero4, zero4};
        // ---- S: consume A=K-d0(t), B=K-d1(t) (+Qhi); stage V0(t)->C ----
        WAIT_BAR(0)                       // Q=[Klo(t),Khi(t)] both landed (staged >=1 phase ago): trivial
        stgV(j0, 0, C);
        {
            u16x8 kb[8];
            #pragma unroll
            for (int ks = 0; ks < 8; ++ks)
                kb[ks] = FRD(A + (ks >> 1) * 4096, wn * 16 + l16, (ks & 1) * 32 + quad * 8);
            asm volatile("s_waitcnt lgkmcnt(0)" ::: "memory");
            __builtin_amdgcn_sched_barrier(0);
            __builtin_amdgcn_s_setprio(1);
            #pragma unroll
            for (int ks = 0; ks < 8; ++ks)
                #pragma unroll
                for (int m = 0; m < 2; ++m) aS[m] = mma16<0>(qa[m][ks], kb[ks], aS[m]);
            __builtin_amdgcn_s_setprio(0);
            // second K half (d-hi), Q-hi A-operand from LDS; no barrier needed in between
            #pragma unroll
            for (int ks = 0; ks < 8; ++ks)
                kb[ks] = FRD(B + (ks >> 1) * 4096, wn * 16 + l16, (ks & 1) * 32 + quad * 8);
            asm volatile("s_waitcnt lgkmcnt(0)" ::: "memory");
            __builtin_amdgcn_sched_barrier(0);
            __builtin_amdgcn_s_setprio(1);
            #pragma unroll
            for (int ks = 0; ks < 8; ++ks)
                #pragma unroll
                for (int m = 0; m < 2; ++m) {
                    u16x8 aq = FRD(Qhi + (ks >> 1) * 4096, wm * 32 + m * 16 + l16, (ks & 1) * 32 + quad * 8);
                    aS[m] = mma16<0>(aq, kb[ks], aS[m]);
                }
            __builtin_amdgcn_s_setprio(0);
        }
        // ---- PV0: consume C=V0(t); stage V1(t)->A + K0(t+1)->B; exp + P (midbar) ----
        WAIT_BAR(0)                       // Q=[V0(t)] staged at S start (~1 S-cluster ago): trivial
        stgV(j0, 1, A);
        if (t + 1 < NT) stgK(j1, 0, B);
        #pragma unroll
        for (int m = 0; m < 2; ++m)
            #pragma unroll
            for (int r = 0; r < 4; ++r) {
                float p = __expf(aS[m][r]);
                rsum[m][r] += p;
                int il = wm * 32 + m * 16 + quad * 4 + r;
                bf16 h = __float2bfloat16(p);
                P_l[il * 64 + ((wn * 16 + l16) ^ ((il & 7) * 8))] = __builtin_bit_cast(unsigned short, h);
            }
        asm volatile("s_waitcnt lgkmcnt(0)" ::: "memory");  // P writes retired
        __builtin_amdgcn_s_barrier();                       // P visible to all waves
        __builtin_amdgcn_sched_barrier(0);
        {
            u16x8 fb[4][2];
            #pragma unroll
            for (int nn = 0; nn < 4; ++nn)
                #pragma unroll
                for (int ks = 0; ks < 2; ++ks)
                    fb[nn][ks] = FRD(C + wn * 4096, nn * 16 + l16, ks * 32 + quad * 8);
            #pragma unroll
            for (int m = 0; m < 2; ++m)
                #pragma unroll
                for (int ks = 0; ks < 2; ++ks)
                    pa[m][ks] = *(const u16x8*)&P_l[(wm * 32 + m * 16 + l16) * 64 + ((ks * 32 + quad * 8) ^ lsw)];
            asm volatile("s_waitcnt lgkmcnt(0)" ::: "memory");
            __builtin_amdgcn_sched_barrier(0);
            __builtin_amdgcn_s_setprio(1);
            #pragma unroll
            for (int m = 0; m < 2; ++m)
                #pragma unroll
                for (int nn = 0; nn < 4; ++nn)
                    #pragma unroll
                    for (int ks = 0; ks < 2; ++ks)
                        acc[m][nn] = mma16<0>(pa[m][ks], fb[nn][ks], acc[m][nn]);
            __builtin_amdgcn_s_setprio(0);
        }
        // ---- PV1: consume A=V1(t); stage K1(t+1)->C ----
        if (t + 1 < NT) { WAIT_BAR(4) }   // drain V1(t); K0(t+1) stays in flight
        else            { WAIT_BAR(0) }
        if (t + 1 < NT) stgK(j1, 1, C);
        {
            u16x8 fb[4][2];
            #pragma unroll
            for (int nn = 0; nn < 4; ++nn)
                #pragma unroll
                for (int ks = 0; ks < 2; ++ks)
                    fb[nn][ks] = FRD(A + wn * 4096, nn * 16 + l16, ks * 32 + quad * 8);
            asm volatile("s_waitcnt lgkmcnt(0)" ::: "memory");
            __builtin_amdgcn_sched_barrier(0);
            __builtin_amdgcn_s_setprio(1);
            #pragma unroll
            for (int m = 0; m < 2; ++m)
                #pragma unroll
                for (int nn = 0; nn < 4; ++nn)
                    #pragma unroll
                    for (int ks = 0; ks < 2; ++ks)
                        acc[m][4 + nn] = mma16<0>(pa[m][ks], fb[nn][ks], acc[m][4 + nn]);
            __builtin_amdgcn_s_setprio(0);
        }
        // rotate ring: next tile's (K0,K1,V0) slots
        unsigned short* tmp = A; A = B; B = C; C = tmp;
    }
#undef FRD
#undef WAIT_BAR

    // ---- lsum: per-lane partials -> row sums -> global atomics (j-split blocks both add) ----
    #pragma unroll
    for (int m = 0; m < 2; ++m)
        #pragma unroll
        for (int r = 0; r < 4; ++r) {
            float v = rsum[m][r];
            v += __shfl_xor(v, 1); v += __shfl_xor(v, 2); v += __shfl_xor(v, 4); v += __shfl_xor(v, 8);
            if (l16 == 0)
                atomicAdd(lsum + (size_t)bt * Nsp + i0 + wm * 32 + m * 16 + quad * 4 + r, v);
        }
    __syncthreads();
    // ---- O epilogue: LDS transpose (pitch 520, row&7 XOR) -> 16B coalesced partial stores ----
    #pragma unroll
    for (int m = 0; m < 2; ++m)
        #pragma unroll
        for (int h = 0; h < 2; ++h)
            #pragma unroll
            for (int nn = 0; nn < 4; ++nn) {
                int colL = h * 256 + wn * 64 + nn * 16 + l16;
                int rowB = wm * 32 + m * 16 + quad * 4;
                #pragma unroll
                for (int r = 0; r < 4; ++r) {
                    int rw = rowB + r;
                    bf16 hv = __float2bfloat16(acc[m][h * 4 + nn][r]);
                    smem[rw * 520 + (colL ^ ((rw & 7) * 8))] = __builtin_bit_cast(unsigned short, hv);
                }
            }
    __syncthreads();
    const int orow = tid >> 3, ocb = tid & 7;
    unsigned short* od = (unsigned short*)Opart_ + (size_t)js * ((size_t)NB * Nsp * Cdim) +
                         ((size_t)bt * Nsp + i0 + orow) * Cdim;
    #pragma unroll
    for (int it = 0; it < 8; ++it) {
        int cc = ocb + it * 8;
        u16x8 hv = *(const u16x8*)&smem[orow * 520 + ((cc * 8) ^ ((orow & 7) * 8))];
        *(u16x8*)(od + cc * 8) = hv;
    }
}

// ---------------------------------------------------------------- sum 2 bf16 j-split partials, /l -> bf16
__global__ __launch_bounds__(256) void k_reduce2(const bf16* __restrict__ P, const float* __restrict__ lsum,
                                                 bf16* __restrict__ O) {
    constexpr size_t SL = (size_t)NB * Nsp * Cdim;  // 4194304 elems per slab
    size_t i = ((size_t)blockIdx.x * 256 + threadIdx.x) * 8;
    float linv = 1.f / lsum[i >> 9];  // flat/512 = b*Nsp + row
    union { bf16 h[8]; uint4 u; } a, b, r;
    a.u = *(const uint4*)(P + i);
    b.u = *(const uint4*)(P + SL + i);
    #pragma unroll
    for (int e = 0; e < 8; ++e) {
        float s = __bfloat162float(a.h[e]) + __bfloat162float(b.h[e]);
        r.h[e] = __float2bfloat16(s * linv);
    }
    *(uint4*)(O + i) = r.u;
}

// ---------------------------------------------------------------- launcher
extern "C" void kernel_launch(void* const* d_in, const int* in_sizes, int n_in,
                              void* d_out, int out_size, void* d_ws, size_t ws_size,
                              hipStream_t stream) {
    const float* x     = (const float*)d_in[0];
    const float* gamma = (const float*)d_in[1];
    const float* beta  = (const float*)d_in[2];
    const float* wq = (const float*)d_in[3];  const float* bq = (const float*)d_in[4];
    const float* wk = (const float*)d_in[5];  const float* bk = (const float*)d_in[6];
    const float* wv = (const float*)d_in[7];  const float* bv = (const float*)d_in[8];
    const float* wo = (const float*)d_in[9];  const float* bo = (const float*)d_in[10];
    float* out = (float*)d_out;

    // workspace layout
    char* ws = (char*)d_ws;
    float* stats = (float*)ws;
    size_t off = 1024;
    float* lsum = (float*)(ws + off); off += (size_t)NB * Nsp * 4 + 1024;  // 32 KB row sums
    bf16* wqkb = (bf16*)(ws + off); off += (size_t)1024 * 512 * 2;        // 1 MB  [1024][512] Q then K
    bf16* wvb  = (bf16*)(ws + off); off += (size_t)512 * 512 * 2;         // 0.5 MB
    bf16* wob  = (bf16*)(ws + off); off += (size_t)512 * 512 * 2;         // 0.5 MB
    bf16* Vm   = (bf16*)(ws + off); off += (size_t)NB * Nsp * Cdim * 2;   // 8 MB  [b][c][j]
    bf16* Ot   = (bf16*)(ws + off); off += (size_t)NB * Nsp * Cdim * 2;   // 8 MB  [b][i][c]
    bf16* Opart = (bf16*)(ws + off); off += (size_t)2 * NB * Nsp * Cdim * 2;  // 16 MB: 2 j-split slabs
    bf16* ht   = (bf16*)(ws + off); off += (size_t)NB * Nsp * Cdim * 2;   // 8 MB  [b][n][c]
    bf16* QKt  = (bf16*)(ws + off); off += (size_t)NB * Nsp * 1024 * 2;   // 16 MB [b][n][1024]

    // fused: weight cvt (0..255) + lsum zero (256) + groupnorm stats (257..320)
    k_cvt_all<<<321, 256, 0, stream>>>(wq, wk, wv, wo, wqkb, wvb, wob, lsum, x, stats);
    k_gn_apply<<<dim3(64, 2), 256, 0, stream>>>(x, stats, gamma, beta, ht);

    const long long hs = (long long)Nsp * Cdim;    // 2097152
    const long long qs = (long long)Nsp * 1024;    // 4194304

    // fused Q+K proj: QKt[i][co'] = (sum_k ht[i][k] wqk[co'][k] + b) (*SCALE for Q half)
    k_gemm_nt<128, 0, 0, 3, 0, 1, 0><<<dim3(32, 8, 2), 256, 0, stream>>>(
        ht, hs, 512, wqkb, 0, 512, bq, bk, nullptr, 0, nullptr, QKt, qs, 1024, 512);
    // V: Vm[co][j] = sum_k wv[co][k] ht[j][k] + bv  (M=512, N=4096, bf16 out)
    k_gemm_nt<128, 0, 0, 1, 0, 1, 0><<<dim3(4, 32, 2), 256, 0, stream>>>(
        wvb, 0, 512, ht, hs, 512, bv, nullptr, nullptr, 0, nullptr, Vm, hs, 4096, 512);
    // fused attention: O_partial (2 j-split slabs) + lsum
    k_attn<<<dim3(64, 2, 2), 512, 0, stream>>>(QKt, Vm, lsum, Opart);
    // combine j-split partials, divide by row sums -> Ot bf16
    k_reduce2<<<2048, 256, 0, stream>>>(Opart, lsum, Ot);
    // out[co][i] = x[co][i] + bo[co] + sum_k wo[co][k] Ot[i][k]  (fp32 out + residual)
    k_gemm_nt<128, 0, 2, 1, 1, 1, 0><<<dim3(4, 32, 2), 256, 0, stream>>>(
        wob, 0, 512, Ot, hs, 512, bo, nullptr, x, hs, nullptr, out, hs, 4096, 512);
}

// Round 13
// 247.684 us; speedup vs baseline: 1.0128x; 1.0128x over previous
//
#include <hip/hip_runtime.h>
#include <hip/hip_bf16.h>

typedef __bf16 bf16x8 __attribute__((ext_vector_type(8)));
typedef _Float16 f16x8 __attribute__((ext_vector_type(8)));
typedef unsigned short u16x8 __attribute__((ext_vector_type(8)));
typedef float f32x4 __attribute__((ext_vector_type(4)));
using bf16 = __hip_bfloat16;

constexpr int Cdim = 512;   // channels
constexpr int Nsp  = 4096;  // d*h*w
constexpr int NB   = 2;     // batch
constexpr float SCALE = 0.04419417382415922f;  // 512^-0.5
constexpr int EPITCH = 132; // epilogue LDS pitch (elems) for k_gemm_nt

// async 16B global->LDS (m97 pattern). LDS dest must be wave-uniform base + lane*16.
#define GL2LDS(gaddr, laddr)                                                              \
    __builtin_amdgcn_global_load_lds((const __attribute__((address_space(1))) void*)(gaddr), \
                                     (__attribute__((address_space(3))) void*)(laddr), 16, 0, 0)

// stage one 8KB [64 rows][64 elems] bf16 subtile: 1 GL2LDS per thread (512 thd),
// linear LDS dest, XOR-pre-swizzled global source chunk (verified k_gemm_nt pattern).
#define STG1(dst, src, ld) { int _o = tid * 16, _r = _o >> 7, _c = ((_o >> 4) ^ _r) & 7;      \
    GL2LDS((const unsigned short*)(src) + (size_t)_r * (ld) + _c * 8,                          \
           (unsigned short*)(dst) + (_o >> 1)); }

// ---------------------------------------------------------------- weights fp32 -> bf16 + zero lsum + GN stats,
// one launch: blocks 0..255 cvt, 256 zero-lsum, 257..320 groupnorm stats (64 b*g blocks).
__global__ __launch_bounds__(256) void k_cvt_all(const float* __restrict__ wq, const float* __restrict__ wk,
                                                 const float* __restrict__ wv, const float* __restrict__ wo,
                                                 bf16* __restrict__ wqkb, bf16* __restrict__ wvb,
                                                 bf16* __restrict__ wob, float* __restrict__ lsum,
                                                 const float* __restrict__ x, float* __restrict__ stats) {
    __shared__ float rs[4], rs2[4];
    if (blockIdx.x >= 257) {  // groupnorm stats for bg = blockIdx.x - 257
        int bg = blockIdx.x - 257;  // 0..63
        const float4* p = (const float4*)(x + (size_t)bg * (16 * 4096));
        float s = 0.f, s2 = 0.f;
        for (int i = threadIdx.x; i < 16384; i += 256) {
            float4 v = p[i];
            s  += v.x + v.y + v.z + v.w;
            s2 += v.x * v.x + v.y * v.y + v.z * v.z + v.w * v.w;
        }
        #pragma unroll
        for (int off = 32; off; off >>= 1) { s += __shfl_xor(s, off); s2 += __shfl_xor(s2, off); }
        int w = threadIdx.x >> 6;
        if ((threadIdx.x & 63) == 0) { rs[w] = s; rs2[w] = s2; }
        __syncthreads();
        if (threadIdx.x == 0) {
            float S = rs[0] + rs[1] + rs[2] + rs[3];
            float S2 = rs2[0] + rs2[1] + rs2[2] + rs2[3];
            float mean = S * (1.f / 65536.f);
            float var  = S2 * (1.f / 65536.f) - mean * mean;
            stats[bg * 2]     = mean;
            stats[bg * 2 + 1] = rsqrtf(var + 1e-6f);
        }
        return;
    }
    if (blockIdx.x == 256) {  // zero 8192-float lsum
        #pragma unroll
        for (int j = 0; j < 8; ++j)
            ((float4*)lsum)[8 * threadIdx.x + j] = float4{0.f, 0.f, 0.f, 0.f};
        return;
    }
    int i = blockIdx.x * 256 + threadIdx.x;  // 65536 float4 groups per weight
    float4 q = ((const float4*)wq)[i];
    float4 k = ((const float4*)wk)[i];
    float4 v = ((const float4*)wv)[i];
    float4 o = ((const float4*)wo)[i];
    bf16* dq = wqkb + (size_t)i * 4;
    dq[0] = __float2bfloat16(q.x); dq[1] = __float2bfloat16(q.y);
    dq[2] = __float2bfloat16(q.z); dq[3] = __float2bfloat16(q.w);
    bf16* dk = wqkb + 262144 + (size_t)i * 4;
    dk[0] = __float2bfloat16(k.x); dk[1] = __float2bfloat16(k.y);
    dk[2] = __float2bfloat16(k.z); dk[3] = __float2bfloat16(k.w);
    bf16* dv = wvb + (size_t)i * 4;
    dv[0] = __float2bfloat16(v.x); dv[1] = __float2bfloat16(v.y);
    dv[2] = __float2bfloat16(v.z); dv[3] = __float2bfloat16(v.w);
    bf16* dw = wob + (size_t)i * 4;
    dw[0] = __float2bfloat16(o.x); dw[1] = __float2bfloat16(o.y);
    dw[2] = __float2bfloat16(o.z); dw[3] = __float2bfloat16(o.w);
}

// ---------------------------------------------------------------- groupnorm apply + transpose -> ht[b,n,c] bf16
__global__ __launch_bounds__(256) void k_gn_apply(const float* __restrict__ x, const float* __restrict__ stats,
                                                  const float* __restrict__ gamma, const float* __restrict__ beta,
                                                  bf16* __restrict__ ht) {
    int b = blockIdx.y;
    int n0 = blockIdx.x * 64;
    int tid = threadIdx.x;
    __shared__ float tile[64][65];
    int nn_l = tid & 63, cc0 = tid >> 6;
    int cc_w = tid & 63, nn0 = tid >> 6;
    for (int c0 = 0; c0 < Cdim; c0 += 64) {
        #pragma unroll
        for (int p = 0; p < 16; ++p) {
            int cc = p * 4 + cc0;
            tile[cc][nn_l] = x[(size_t)(b * Cdim + c0 + cc) * Nsp + n0 + nn_l];
        }
        __syncthreads();
        int c = c0 + cc_w, g = c >> 4;
        float mean = stats[(b * 32 + g) * 2];
        float rstd = stats[(b * 32 + g) * 2 + 1];
        float ga = gamma[c], be = beta[c];
        #pragma unroll
        for (int p = 0; p < 16; ++p) {
            int nn = p * 4 + nn0;
            float v = tile[cc_w][nn];
            ht[(size_t)(b * Nsp + n0 + nn) * Cdim + c] = __float2bfloat16((v - mean) * rstd * ga + be);
        }
        __syncthreads();
    }
}

// ---------------------------------------------------------------- MFMA dtype dispatch
template <int DT>
__device__ __forceinline__ f32x4 mma16(u16x8 a, u16x8 b, f32x4 c) {
    if constexpr (DT == 0)
        return __builtin_amdgcn_mfma_f32_16x16x32_bf16(__builtin_bit_cast(bf16x8, a),
                                                       __builtin_bit_cast(bf16x8, b), c, 0, 0, 0);
    else
        return __builtin_amdgcn_mfma_f32_16x16x32_f16(__builtin_bit_cast(f16x8, a),
                                                      __builtin_bit_cast(f16x8, b), c, 0, 0, 0);
}

// ---------------------------------------------------------------- NT GEMM (m97 structure) + XOR-swizzled LDS
// Used for QK-proj, V-proj, O-proj (proven round-0 config).
template <int BM, int DT, int OUTT, int BIAS, int RESID, int SPLITK, int EXPSUM>
__global__ __launch_bounds__(256) void k_gemm_nt(
    const void* __restrict__ Av, long long As, int lda,
    const void* __restrict__ Bv, long long Bs, int ldb,
    const float* __restrict__ bias, const float* __restrict__ bias2,
    const float* __restrict__ resid, long long Rs,
    float* __restrict__ lsum,
    void* __restrict__ outv, long long Os,
    int N, int K) {
    constexpr int MT = BM / 32;       // m-tiles per wave
    constexpr int SME_STAGE = (BM + 128) * 64;
    constexpr int SME_EPI   = BM * EPITCH;
    constexpr int SME = SME_STAGE > SME_EPI ? SME_STAGE : SME_EPI;
    const int bm = blockIdx.x, bn = blockIdx.y, zz = blockIdx.z;
    const int bt  = (SPLITK > 1) ? (zz % NB) : zz;
    const int ksl = (SPLITK > 1) ? (zz / NB) : 0;
    const int Kc = K / SPLITK;
    const int kbeg = ksl * Kc;
    const unsigned short* Ab = (const unsigned short*)Av + (size_t)bt * As;
    const unsigned short* Bb = (const unsigned short*)Bv + (size_t)bt * Bs;
    const int tid = threadIdx.x, lane = tid & 63, w = tid >> 6;
    const int quad = lane >> 4, l16 = lane & 15;
    const int wm = w >> 1, wn = w & 1;
    __shared__ __align__(16) unsigned short smem[SME];
    unsigned short (*Asub)[64] = (unsigned short(*)[64])smem;
    unsigned short (*Bsub)[64] = (unsigned short(*)[64])(smem + BM * 64);
    f32x4 zero4 = {0.f, 0.f, 0.f, 0.f};
    f32x4 acc[MT][4];
    #pragma unroll
    for (int i = 0; i < MT; ++i)
        #pragma unroll
        for (int j = 0; j < 4; ++j) acc[i][j] = zero4;
    const int row0 = bm * BM, col0 = bn * 128;
    const size_t ldab = (size_t)lda * 2, ldbb = (size_t)ldb * 2;
    const int lsw = (l16 & 7) * 8;  // fragment-read swizzle (elems)
    for (int k0 = kbeg; k0 < kbeg + Kc; k0 += 64) {
        const char* Abase = (const char*)Ab + (size_t)k0 * 2;
        const char* Bbase = (const char*)Bb + (size_t)k0 * 2;
        #pragma unroll
        for (int p = 0; p < BM / 32; ++p) {
            int o = p * 4096 + tid * 16;         // byte offset into A LDS tile
            int r = o >> 7;                      // row (128 B per row)
            int cs = ((o >> 4) ^ r) & 7;         // swizzled source chunk
            GL2LDS(Abase + (size_t)(row0 + r) * ldab + cs * 16, (char*)smem + o);
        }
        #pragma unroll
        for (int p = 0; p < 4; ++p) {
            int o = p * 4096 + tid * 16;
            int r = o >> 7;
            int cs = ((o >> 4) ^ r) & 7;
            GL2LDS(Bbase + (size_t)(col0 + r) * ldbb + cs * 16, (char*)smem + BM * 128 + o);
        }
        __syncthreads();
        #pragma unroll
        for (int ks = 0; ks < 2; ++ks) {
            u16x8 af[MT], bfr[4];
            #pragma unroll
            for (int t = 0; t < MT; ++t)
                af[t] = *(const u16x8*)&Asub[wm * (BM / 2) + t * 16 + l16][(ks * 32 + quad * 8) ^ lsw];
            #pragma unroll
            for (int t = 0; t < 4; ++t)
                bfr[t] = *(const u16x8*)&Bsub[wn * 64 + t * 16 + l16][(ks * 32 + quad * 8) ^ lsw];
            #pragma unroll
            for (int tm = 0; tm < MT; ++tm)
                #pragma unroll
                for (int tn = 0; tn < 4; ++tn) acc[tm][tn] = mma16<DT>(af[tm], bfr[tn], acc[tm][tn]);
        }
        __syncthreads();
    }

    if constexpr (OUTT == 2) {
        // scalar fp32 epilogue (final projection: bias + residual + fp32 out)
        #pragma unroll
        for (int tm = 0; tm < MT; ++tm)
            #pragma unroll
            for (int tn = 0; tn < 4; ++tn)
                #pragma unroll
                for (int r = 0; r < 4; ++r) {
                    int row = row0 + wm * (BM / 2) + tm * 16 + quad * 4 + r;
                    int col = col0 + wn * 64 + tn * 16 + l16;
                    float v = acc[tm][tn][r];
                    if constexpr (BIAS == 1) v += bias[row];
                    else if constexpr (BIAS == 2) v += bias[col];
                    if constexpr (RESID) v += resid[(size_t)bt * Rs + (size_t)row * N + col];
                    ((float*)outv)[(size_t)zz * Os + (size_t)row * N + col] = v;
                }
    } else {
        // ---- LDS-transpose epilogue (2-byte outputs) ----
        #pragma unroll
        for (int tn = 0; tn < 4; ++tn) {
            int colL = wn * 64 + tn * 16 + l16;
            float bc = 0.f;
            if constexpr (BIAS == 2) bc = bias[col0 + colL];
            else if constexpr (BIAS == 3) {
                int col = col0 + colL;
                bc = (col < 512) ? bias[col] : bias2[col - 512];
            }
            #pragma unroll
            for (int tm = 0; tm < MT; ++tm)
                #pragma unroll
                for (int r = 0; r < 4; ++r) {
                    int rowL = wm * (BM / 2) + tm * 16 + quad * 4 + r;
                    float v = acc[tm][tn][r];
                    if constexpr (BIAS == 1) v += bias[row0 + rowL];
                    else if constexpr (BIAS == 2) v += bc;
                    else if constexpr (BIAS == 3) {
                        int col = col0 + colL;
                        v = (col < 512) ? (v + bc) * SCALE : v + bc;
                    }
                    if constexpr (EXPSUM) v = __expf(v);
                    unsigned short hv;
                    if constexpr (OUTT == 1) { _Float16 h = (_Float16)v; hv = __builtin_bit_cast(unsigned short, h); }
                    else { bf16 h = __float2bfloat16(v); hv = __builtin_bit_cast(unsigned short, h); }
                    smem[rowL * EPITCH + colL] = hv;
                }
        }
        __syncthreads();
        // read phase: chunk = tid&15 (8 cols), rows (tid>>4)*(BM/16) + i; 16B coalesced stores
        const int cch = (tid & 15) * 8;
        const int rg  = (tid >> 4) * (BM / 16);
        #pragma unroll
        for (int i = 0; i < BM / 16; ++i) {
            int rowL = rg + i;
            u16x8 hv = *(const u16x8*)&smem[rowL * EPITCH + cch];
            *(u16x8*)((unsigned short*)outv + (size_t)zz * Os + (size_t)(row0 + rowL) * N + col0 + cch) = hv;
            if constexpr (EXPSUM) {
                float ps = 0.f;
                #pragma unroll
                for (int e = 0; e < 8; ++e) {
                    bf16 h = __builtin_bit_cast(bf16, hv[e]);
                    ps += __bfloat162float(h);
                }
                #pragma unroll
                for (int m = 1; m < 16; m <<= 1) ps += __shfl_xor(ps, m);
                if ((lane & 15) == 0) atomicAdd(lsum + (size_t)bt * Nsp + row0 + rowL, ps);
            }
        }
    }
}

// ---------------------------------------------------------------- fused attention v4 (verified best, r8/r11):
// half-Q-hoist + ring-3. qa[2][8] (64 VGPR) holds Q-d-lo; Q-d-hi resident in LDS (32 KB).
// Ring-3 of 32KB slots + Qhi + P = 136 KB, counted vmcnt(4) per phase (one half always in flight).
// Slots rotate (A,B,C) <- (B,C,A) per tile: S0 consumes A(K-d0) stages V0->C; S1 consumes B(K-d1)+Qhi
// stages V1->A; PV0 consumes C(V-c0) stages K0(t+1)->B (+exp/P mid-barrier); PV1 consumes A(V-c1)
// stages K1(t+1)->C. vmcnt(0) only at the last tile. LDS reads/tile/wave: 52.
// SETTLED LAWS (r9/r10/r12): (1) arch-VGPR envelope ~128 — full-Q-hoist and AGPR-anchored Q both
// spill (WRITE 17->44 MB); (2) barriers are cheap, PREFETCH DISTANCE is not — merging S0+S1 (r12)
// cut a barrier but halved V1's prefetch cover and cost 6us. Do not change the phase structure.
__global__ __launch_bounds__(512, 2) void k_attn(const bf16* __restrict__ QKt_, const bf16* __restrict__ Vm_,
                                                 float* __restrict__ lsum, bf16* __restrict__ Opart_) {
    constexpr int NT = 32;
    const int bx = blockIdx.x, js = blockIdx.y, bt = blockIdx.z;
    const int i0 = bx * 64;
    const int jbase = js * 2048;
    const unsigned short* Qb = (const unsigned short*)QKt_ + (size_t)bt * ((size_t)Nsp * 1024);
    const unsigned short* Vb = (const unsigned short*)Vm_ + (size_t)bt * ((size_t)Nsp * Cdim);  // [c][j] ld 4096
    const int tid = threadIdx.x, lane = tid & 63, w = tid >> 6;
    const int quad = lane >> 4, l16 = lane & 15;
    const int wm = w >> 2, wn = w & 3;   // 2 m-waves x 4 n-waves
    const int lsw = (l16 & 7) * 8;
    __shared__ __align__(16) unsigned short smem[69632];   // ring 3x16384 | Qhi 16384 | P 4096 (139264 B)
    unsigned short* Qhi = smem + 49152;
    unsigned short* P_l = smem + 65536;

    auto stgK = [&](int jj, int dh, unsigned short* dst) {
        #pragma unroll
        for (int s = 0; s < 4; ++s)
            STG1(dst + s * 4096, Qb + (size_t)jj * 1024 + 512 + dh * 256 + s * 64, 1024);
    };
    auto stgV = [&](int jj, int ch, unsigned short* dst) {
        #pragma unroll
        for (int s = 0; s < 4; ++s)
            STG1(dst + s * 4096, Vb + (size_t)(ch * 256 + s * 64) * 4096 + jj, 4096);
    };

#define FRD(base, row, kc) (*(const u16x8*)&(base)[(row) * 64 + ((kc) ^ lsw)])
#define WAIT_BAR(N) \
    asm volatile("s_waitcnt vmcnt(" #N ")" ::: "memory"); \
    __builtin_amdgcn_s_barrier(); \
    __builtin_amdgcn_sched_barrier(0);

    f32x4 zero4 = {0.f, 0.f, 0.f, 0.f};
    f32x4 acc[2][8];
    #pragma unroll
    for (int m = 0; m < 2; ++m)
        #pragma unroll
        for (int n = 0; n < 8; ++n) acc[m][n] = zero4;
    float rsum[2][4] = {{0.f, 0.f, 0.f, 0.f}, {0.f, 0.f, 0.f, 0.f}};
    u16x8 pa[2][2];

    unsigned short* A = smem;            // tile-0: K-d0 slot
    unsigned short* B = smem + 16384;    // tile-0: K-d1 slot
    unsigned short* C = smem + 32768;    // tile-0: V-c0 slot (Q-lo temp in prologue)

    // ---- prologue: Q-lo -> C (temp), Q-hi -> Qhi, K0(0)->A, K1(0)->B ----
    #pragma unroll
    for (int s = 0; s < 4; ++s) STG1(C + s * 4096, Qb + (size_t)i0 * 1024 + s * 64, 1024);
    #pragma unroll
    for (int s = 0; s < 4; ++s) STG1(Qhi + s * 4096, Qb + (size_t)i0 * 1024 + 256 + s * 64, 1024);
    stgK(jbase, 0, A);
    stgK(jbase, 1, B);
    WAIT_BAR(8)                          // Q-lo/Q-hi landed; K halves may be in flight
    u16x8 qa[2][8];                      // Q-d-lo in registers (64 VGPR)
    #pragma unroll
    for (int m = 0; m < 2; ++m)
        #pragma unroll
        for (int ks = 0; ks < 8; ++ks)
            qa[m][ks] = FRD(C + (ks >> 1) * 4096, wm * 32 + m * 16 + l16, (ks & 1) * 32 + quad * 8);
    asm volatile("s_waitcnt lgkmcnt(0)" ::: "memory");
    __builtin_amdgcn_s_barrier();        // C free for V0(0)
    __builtin_amdgcn_sched_barrier(0);

    for (int t = 0; t < NT; ++t) {
        const int j0 = jbase + t * 64;
        const int j1 = j0 + 64;
        f32x4 aS[2] = {zero4, zero4};
        // ---- S0: consume A = K-d0(t); stage V0(t)->C ----
        WAIT_BAR(4)
        stgV(j0, 0, C);
        {
            u16x8 kb[8];
            #pragma unroll
            for (int ks = 0; ks < 8; ++ks)
                kb[ks] = FRD(A + (ks >> 1) * 4096, wn * 16 + l16, (ks & 1) * 32 + quad * 8);
            asm volatile("s_waitcnt lgkmcnt(0)" ::: "memory");
            __builtin_amdgcn_sched_barrier(0);
            __builtin_amdgcn_s_setprio(1);
            #pragma unroll
            for (int ks = 0; ks < 8; ++ks)
                #pragma unroll
                for (int m = 0; m < 2; ++m) aS[m] = mma16<0>(qa[m][ks], kb[ks], aS[m]);
            __builtin_amdgcn_s_setprio(0);
        }
        // ---- S1: consume B = K-d1(t) + Q-hi from LDS; stage V1(t)->A ----
        WAIT_BAR(4)
        stgV(j0, 1, A);
        {
            u16x8 kb[8];
            #pragma unroll
            for (int ks = 0; ks < 8; ++ks)
                kb[ks] = FRD(B + (ks >> 1) * 4096, wn * 16 + l16, (ks & 1) * 32 + quad * 8);
            asm volatile("s_waitcnt lgkmcnt(0)" ::: "memory");
            __builtin_amdgcn_sched_barrier(0);
            __builtin_amdgcn_s_setprio(1);
            #pragma unroll
            for (int ks = 0; ks < 8; ++ks)
                #pragma unroll
                for (int m = 0; m < 2; ++m) {
                    u16x8 aq = FRD(Qhi + (ks >> 1) * 4096, wm * 32 + m * 16 + l16, (ks & 1) * 32 + quad * 8);
                    aS[m] = mma16<0>(aq, kb[ks], aS[m]);
                }
            __builtin_amdgcn_s_setprio(0);
        }
        // ---- PV0: consume C = V-c0(t); stage K0(t+1)->B; exp + P (mid-barrier) ----
        WAIT_BAR(4)
        if (t + 1 < NT) stgK(j1, 0, B);
        #pragma unroll
        for (int m = 0; m < 2; ++m)
            #pragma unroll
            for (int r = 0; r < 4; ++r) {
                float p = __expf(aS[m][r]);
                rsum[m][r] += p;
                int il = wm * 32 + m * 16 + quad * 4 + r;
                bf16 h = __float2bfloat16(p);
                P_l[il * 64 + ((wn * 16 + l16) ^ ((il & 7) * 8))] = __builtin_bit_cast(unsigned short, h);
            }
        asm volatile("s_waitcnt lgkmcnt(0)" ::: "memory");  // P writes retired
        __builtin_amdgcn_s_barrier();                       // P visible to all waves
        __builtin_amdgcn_sched_barrier(0);
        {
            u16x8 fb[4][2];
            #pragma unroll
            for (int nn = 0; nn < 4; ++nn)
                #pragma unroll
                for (int ks = 0; ks < 2; ++ks)
                    fb[nn][ks] = FRD(C + wn * 4096, nn * 16 + l16, ks * 32 + quad * 8);
            #pragma unroll
            for (int m = 0; m < 2; ++m)
                #pragma unroll
                for (int ks = 0; ks < 2; ++ks)
                    pa[m][ks] = *(const u16x8*)&P_l[(wm * 32 + m * 16 + l16) * 64 + ((ks * 32 + quad * 8) ^ lsw)];
            asm volatile("s_waitcnt lgkmcnt(0)" ::: "memory");
            __builtin_amdgcn_sched_barrier(0);
            __builtin_amdgcn_s_setprio(1);
            #pragma unroll
            for (int m = 0; m < 2; ++m)
                #pragma unroll
                for (int nn = 0; nn < 4; ++nn)
                    #pragma unroll
                    for (int ks = 0; ks < 2; ++ks)
                        acc[m][nn] = mma16<0>(pa[m][ks], fb[nn][ks], acc[m][nn]);
            __builtin_amdgcn_s_setprio(0);
        }
        // ---- PV1: consume A = V-c1(t); stage K1(t+1)->C ----
        if (t + 1 < NT) { WAIT_BAR(4) } else { WAIT_BAR(0) }
        if (t + 1 < NT) stgK(j1, 1, C);
        {
            u16x8 fb[4][2];
            #pragma unroll
            for (int nn = 0; nn < 4; ++nn)
                #pragma unroll
                for (int ks = 0; ks < 2; ++ks)
                    fb[nn][ks] = FRD(A + wn * 4096, nn * 16 + l16, ks * 32 + quad * 8);
            asm volatile("s_waitcnt lgkmcnt(0)" ::: "memory");
            __builtin_amdgcn_sched_barrier(0);
            __builtin_amdgcn_s_setprio(1);
            #pragma unroll
            for (int m = 0; m < 2; ++m)
                #pragma unroll
                for (int nn = 0; nn < 4; ++nn)
                    #pragma unroll
                    for (int ks = 0; ks < 2; ++ks)
                        acc[m][4 + nn] = mma16<0>(pa[m][ks], fb[nn][ks], acc[m][4 + nn]);
            __builtin_amdgcn_s_setprio(0);
        }
        // rotate ring: next tile's (K0,K1,V0) slots
        unsigned short* tmp = A; A = B; B = C; C = tmp;
    }
#undef FRD
#undef WAIT_BAR

    // ---- lsum: per-lane partials -> row sums -> global atomics (j-split blocks both add) ----
    #pragma unroll
    for (int m = 0; m < 2; ++m)
        #pragma unroll
        for (int r = 0; r < 4; ++r) {
            float v = rsum[m][r];
            v += __shfl_xor(v, 1); v += __shfl_xor(v, 2); v += __shfl_xor(v, 4); v += __shfl_xor(v, 8);
            if (l16 == 0)
                atomicAdd(lsum + (size_t)bt * Nsp + i0 + wm * 32 + m * 16 + quad * 4 + r, v);
        }
    __syncthreads();
    // ---- O epilogue: LDS transpose (pitch 520, row&7 XOR) -> 16B coalesced partial stores ----
    #pragma unroll
    for (int m = 0; m < 2; ++m)
        #pragma unroll
        for (int h = 0; h < 2; ++h)
            #pragma unroll
            for (int nn = 0; nn < 4; ++nn) {
                int colL = h * 256 + wn * 64 + nn * 16 + l16;
                int rowB = wm * 32 + m * 16 + quad * 4;
                #pragma unroll
                for (int r = 0; r < 4; ++r) {
                    int rw = rowB + r;
                    bf16 hv = __float2bfloat16(acc[m][h * 4 + nn][r]);
                    smem[rw * 520 + (colL ^ ((rw & 7) * 8))] = __builtin_bit_cast(unsigned short, hv);
                }
            }
    __syncthreads();
    const int orow = tid >> 3, ocb = tid & 7;
    unsigned short* od = (unsigned short*)Opart_ + (size_t)js * ((size_t)NB * Nsp * Cdim) +
                         ((size_t)bt * Nsp + i0 + orow) * Cdim;
    #pragma unroll
    for (int it = 0; it < 8; ++it) {
        int cc = ocb + it * 8;
        u16x8 hv = *(const u16x8*)&smem[orow * 520 + ((cc * 8) ^ ((orow & 7) * 8))];
        *(u16x8*)(od + cc * 8) = hv;
    }
}

// ---------------------------------------------------------------- sum 2 bf16 j-split partials, /l -> bf16
__global__ __launch_bounds__(256) void k_reduce2(const bf16* __restrict__ P, const float* __restrict__ lsum,
                                                 bf16* __restrict__ O) {
    constexpr size_t SL = (size_t)NB * Nsp * Cdim;  // 4194304 elems per slab
    size_t i = ((size_t)blockIdx.x * 256 + threadIdx.x) * 8;
    float linv = 1.f / lsum[i >> 9];  // flat/512 = b*Nsp + row
    union { bf16 h[8]; uint4 u; } a, b, r;
    a.u = *(const uint4*)(P + i);
    b.u = *(const uint4*)(P + SL + i);
    #pragma unroll
    for (int e = 0; e < 8; ++e) {
        float s = __bfloat162float(a.h[e]) + __bfloat162float(b.h[e]);
        r.h[e] = __float2bfloat16(s * linv);
    }
    *(uint4*)(O + i) = r.u;
}

// ---------------------------------------------------------------- launcher
extern "C" void kernel_launch(void* const* d_in, const int* in_sizes, int n_in,
                              void* d_out, int out_size, void* d_ws, size_t ws_size,
                              hipStream_t stream) {
    const float* x     = (const float*)d_in[0];
    const float* gamma = (const float*)d_in[1];
    const float* beta  = (const float*)d_in[2];
    const float* wq = (const float*)d_in[3];  const float* bq = (const float*)d_in[4];
    const float* wk = (const float*)d_in[5];  const float* bk = (const float*)d_in[6];
    const float* wv = (const float*)d_in[7];  const float* bv = (const float*)d_in[8];
    const float* wo = (const float*)d_in[9];  const float* bo = (const float*)d_in[10];
    float* out = (float*)d_out;

    // workspace layout
    char* ws = (char*)d_ws;
    float* stats = (float*)ws;
    size_t off = 1024;
    float* lsum = (float*)(ws + off); off += (size_t)NB * Nsp * 4 + 1024;  // 32 KB row sums
    bf16* wqkb = (bf16*)(ws + off); off += (size_t)1024 * 512 * 2;        // 1 MB  [1024][512] Q then K
    bf16* wvb  = (bf16*)(ws + off); off += (size_t)512 * 512 * 2;         // 0.5 MB
    bf16* wob  = (bf16*)(ws + off); off += (size_t)512 * 512 * 2;         // 0.5 MB
    bf16* Vm   = (bf16*)(ws + off); off += (size_t)NB * Nsp * Cdim * 2;   // 8 MB  [b][c][j]
    bf16* Ot   = (bf16*)(ws + off); off += (size_t)NB * Nsp * Cdim * 2;   // 8 MB  [b][i][c]
    bf16* Opart = (bf16*)(ws + off); off += (size_t)2 * NB * Nsp * Cdim * 2;  // 16 MB: 2 j-split slabs
    bf16* ht   = (bf16*)(ws + off); off += (size_t)NB * Nsp * Cdim * 2;   // 8 MB  [b][n][c]
    bf16* QKt  = (bf16*)(ws + off); off += (size_t)NB * Nsp * 1024 * 2;   // 16 MB [b][n][1024]

    // fused: weight cvt (0..255) + lsum zero (256) + groupnorm stats (257..320)
    k_cvt_all<<<321, 256, 0, stream>>>(wq, wk, wv, wo, wqkb, wvb, wob, lsum, x, stats);
    k_gn_apply<<<dim3(64, 2), 256, 0, stream>>>(x, stats, gamma, beta, ht);

    const long long hs = (long long)Nsp * Cdim;    // 2097152
    const long long qs = (long long)Nsp * 1024;    // 4194304

    // fused Q+K proj: QKt[i][co'] = (sum_k ht[i][k] wqk[co'][k] + b) (*SCALE for Q half)
    k_gemm_nt<128, 0, 0, 3, 0, 1, 0><<<dim3(32, 8, 2), 256, 0, stream>>>(
        ht, hs, 512, wqkb, 0, 512, bq, bk, nullptr, 0, nullptr, QKt, qs, 1024, 512);
    // V: Vm[co][j] = sum_k wv[co][k] ht[j][k] + bv  (M=512, N=4096, bf16 out)
    k_gemm_nt<128, 0, 0, 1, 0, 1, 0><<<dim3(4, 32, 2), 256, 0, stream>>>(
        wvb, 0, 512, ht, hs, 512, bv, nullptr, nullptr, 0, nullptr, Vm, hs, 4096, 512);
    // fused attention: O_partial (2 j-split slabs) + lsum
    k_attn<<<dim3(64, 2, 2), 512, 0, stream>>>(QKt, Vm, lsum, Opart);
    // combine j-split partials, divide by row sums -> Ot bf16
    k_reduce2<<<2048, 256, 0, stream>>>(Opart, lsum, Ot);
    // out[co][i] = x[co][i] + bo[co] + sum_k wo[co][k] Ot[i][k]  (fp32 out + residual)
    k_gemm_nt<128, 0, 2, 1, 1, 1, 0><<<dim3(4, 32, 2), 256, 0, stream>>>(
        wob, 0, 512, Ot, hs, 512, bo, nullptr, x, hs, nullptr, out, hs, 4096, 512);
}

// Round 14
// 223.078 us; speedup vs baseline: 1.1246x; 1.1103x over previous
//
#include <hip/hip_runtime.h>
#include <hip/hip_bf16.h>

typedef __bf16 bf16x8 __attribute__((ext_vector_type(8)));
typedef _Float16 f16x8 __attribute__((ext_vector_type(8)));
typedef unsigned short u16x8 __attribute__((ext_vector_type(8)));
typedef float f32x4 __attribute__((ext_vector_type(4)));
using bf16 = __hip_bfloat16;

constexpr int Cdim = 512;   // channels
constexpr int Nsp  = 4096;  // d*h*w
constexpr int NB   = 2;     // batch
constexpr float SCALE = 0.04419417382415922f;  // 512^-0.5
constexpr int EPITCH = 132; // epilogue LDS pitch (elems) for k_gemm_nt

// async 16B global->LDS (m97 pattern). LDS dest must be wave-uniform base + lane*16.
#define GL2LDS(gaddr, laddr)                                                              \
    __builtin_amdgcn_global_load_lds((const __attribute__((address_space(1))) void*)(gaddr), \
                                     (__attribute__((address_space(3))) void*)(laddr), 16, 0, 0)

// stage one 8KB [64 rows][64 elems] bf16 subtile: 1 GL2LDS per thread (512 thd),
// linear LDS dest, XOR-pre-swizzled global source chunk (verified k_gemm_nt pattern).
#define STG1(dst, src, ld) { int _o = tid * 16, _r = _o >> 7, _c = ((_o >> 4) ^ _r) & 7;      \
    GL2LDS((const unsigned short*)(src) + (size_t)_r * (ld) + _c * 8,                          \
           (unsigned short*)(dst) + (_o >> 1)); }

// ---------------------------------------------------------------- weights fp32 -> bf16 + zero lsum + GN partial
// stats, one launch: blocks 0..255 cvt, 256 zero-lsum, 257..768 partial stats (64 bg x 8 sub-blocks).
// r13 lesson: the old 64-block stats pass covered 25% of CUs -> ~34us for 64MB; 512 partial blocks
// (slot-per-block, no atomics) restore full BW; finalize is folded into k_gn_apply.
__global__ __launch_bounds__(256) void k_cvt_all(const float* __restrict__ wq, const float* __restrict__ wk,
                                                 const float* __restrict__ wv, const float* __restrict__ wo,
                                                 bf16* __restrict__ wqkb, bf16* __restrict__ wvb,
                                                 bf16* __restrict__ wob, float* __restrict__ lsum,
                                                 const float* __restrict__ x, float* __restrict__ stats) {
    __shared__ float rs[4], rs2[4];
    if (blockIdx.x >= 257) {  // partial sums: pb = bg*8 + sub
        int pb = blockIdx.x - 257;            // 0..511
        int bg = pb >> 3, sub = pb & 7;
        const float4* p = (const float4*)(x + (size_t)bg * 65536) + sub * 2048;
        float s = 0.f, s2 = 0.f;
        #pragma unroll
        for (int k = 0; k < 8; ++k) {
            float4 v = p[threadIdx.x + k * 256];
            s  += v.x + v.y + v.z + v.w;
            s2 += v.x * v.x + v.y * v.y + v.z * v.z + v.w * v.w;
        }
        #pragma unroll
        for (int off = 32; off; off >>= 1) { s += __shfl_xor(s, off); s2 += __shfl_xor(s2, off); }
        int w = threadIdx.x >> 6;
        if ((threadIdx.x & 63) == 0) { rs[w] = s; rs2[w] = s2; }
        __syncthreads();
        if (threadIdx.x == 0) {
            stats[pb * 2]     = rs[0] + rs[1] + rs[2] + rs[3];
            stats[pb * 2 + 1] = rs2[0] + rs2[1] + rs2[2] + rs2[3];
        }
        return;
    }
    if (blockIdx.x == 256) {  // zero 8192-float lsum
        #pragma unroll
        for (int j = 0; j < 8; ++j)
            ((float4*)lsum)[8 * threadIdx.x + j] = float4{0.f, 0.f, 0.f, 0.f};
        return;
    }
    int i = blockIdx.x * 256 + threadIdx.x;  // 65536 float4 groups per weight
    float4 q = ((const float4*)wq)[i];
    float4 k = ((const float4*)wk)[i];
    float4 v = ((const float4*)wv)[i];
    float4 o = ((const float4*)wo)[i];
    bf16* dq = wqkb + (size_t)i * 4;
    dq[0] = __float2bfloat16(q.x); dq[1] = __float2bfloat16(q.y);
    dq[2] = __float2bfloat16(q.z); dq[3] = __float2bfloat16(q.w);
    bf16* dk = wqkb + 262144 + (size_t)i * 4;
    dk[0] = __float2bfloat16(k.x); dk[1] = __float2bfloat16(k.y);
    dk[2] = __float2bfloat16(k.z); dk[3] = __float2bfloat16(k.w);
    bf16* dv = wvb + (size_t)i * 4;
    dv[0] = __float2bfloat16(v.x); dv[1] = __float2bfloat16(v.y);
    dv[2] = __float2bfloat16(v.z); dv[3] = __float2bfloat16(v.w);
    bf16* dw = wob + (size_t)i * 4;
    dw[0] = __float2bfloat16(o.x); dw[1] = __float2bfloat16(o.y);
    dw[2] = __float2bfloat16(o.z); dw[3] = __float2bfloat16(o.w);
}

// ---------------------------------------------------------------- groupnorm apply + transpose -> ht[b,n,c] bf16
// r13: 1024 blocks (was 128) — c0 loop unrolled into blockIdx.y; finalizes the 8 partial sums per group.
__global__ __launch_bounds__(256) void k_gn_apply(const float* __restrict__ x, const float* __restrict__ partial,
                                                  const float* __restrict__ gamma, const float* __restrict__ beta,
                                                  bf16* __restrict__ ht) {
    int b = blockIdx.z;
    int c0 = blockIdx.y * 64;
    int n0 = blockIdx.x * 64;
    int tid = threadIdx.x;
    __shared__ float tile[64][65];
    __shared__ float smean[4], srstd[4];
    if (tid < 4) {  // finalize the 4 groups covered by this c0
        int g = (c0 >> 4) + tid;
        const float* pp = partial + (size_t)(b * 32 + g) * 16;
        float S = 0.f, S2 = 0.f;
        #pragma unroll
        for (int k = 0; k < 8; ++k) { S += pp[k * 2]; S2 += pp[k * 2 + 1]; }
        float mean = S * (1.f / 65536.f);
        float var  = S2 * (1.f / 65536.f) - mean * mean;
        smean[tid] = mean;
        srstd[tid] = rsqrtf(var + 1e-6f);
    }
    int nn_l = tid & 63, cc0 = tid >> 6;
    #pragma unroll
    for (int p = 0; p < 16; ++p) {
        int cc = p * 4 + cc0;
        tile[cc][nn_l] = x[(size_t)(b * Cdim + c0 + cc) * Nsp + n0 + nn_l];
    }
    __syncthreads();
    int cc_w = tid & 63, nn0 = tid >> 6;
    int c = c0 + cc_w;
    float mean = smean[cc_w >> 4];
    float rstd = srstd[cc_w >> 4];
    float ga = gamma[c], be = beta[c];
    #pragma unroll
    for (int p = 0; p < 16; ++p) {
        int nn = p * 4 + nn0;
        float v = tile[cc_w][nn];
        ht[(size_t)(b * Nsp + n0 + nn) * Cdim + c] = __float2bfloat16((v - mean) * rstd * ga + be);
    }
}

// ---------------------------------------------------------------- MFMA dtype dispatch
template <int DT>
__device__ __forceinline__ f32x4 mma16(u16x8 a, u16x8 b, f32x4 c) {
    if constexpr (DT == 0)
        return __builtin_amdgcn_mfma_f32_16x16x32_bf16(__builtin_bit_cast(bf16x8, a),
                                                       __builtin_bit_cast(bf16x8, b), c, 0, 0, 0);
    else
        return __builtin_amdgcn_mfma_f32_16x16x32_f16(__builtin_bit_cast(f16x8, a),
                                                      __builtin_bit_cast(f16x8, b), c, 0, 0, 0);
}

// ---------------------------------------------------------------- NT GEMM (m97 structure) + XOR-swizzled LDS
// Used for QK-proj, V-proj, O-proj (proven round-0 config).
template <int BM, int DT, int OUTT, int BIAS, int RESID, int SPLITK, int EXPSUM>
__global__ __launch_bounds__(256) void k_gemm_nt(
    const void* __restrict__ Av, long long As, int lda,
    const void* __restrict__ Bv, long long Bs, int ldb,
    const float* __restrict__ bias, const float* __restrict__ bias2,
    const float* __restrict__ resid, long long Rs,
    float* __restrict__ lsum,
    void* __restrict__ outv, long long Os,
    int N, int K) {
    constexpr int MT = BM / 32;       // m-tiles per wave
    constexpr int SME_STAGE = (BM + 128) * 64;
    constexpr int SME_EPI   = BM * EPITCH;
    constexpr int SME = SME_STAGE > SME_EPI ? SME_STAGE : SME_EPI;
    const int bm = blockIdx.x, bn = blockIdx.y, zz = blockIdx.z;
    const int bt  = (SPLITK > 1) ? (zz % NB) : zz;
    const int ksl = (SPLITK > 1) ? (zz / NB) : 0;
    const int Kc = K / SPLITK;
    const int kbeg = ksl * Kc;
    const unsigned short* Ab = (const unsigned short*)Av + (size_t)bt * As;
    const unsigned short* Bb = (const unsigned short*)Bv + (size_t)bt * Bs;
    const int tid = threadIdx.x, lane = tid & 63, w = tid >> 6;
    const int quad = lane >> 4, l16 = lane & 15;
    const int wm = w >> 1, wn = w & 1;
    __shared__ __align__(16) unsigned short smem[SME];
    unsigned short (*Asub)[64] = (unsigned short(*)[64])smem;
    unsigned short (*Bsub)[64] = (unsigned short(*)[64])(smem + BM * 64);
    f32x4 zero4 = {0.f, 0.f, 0.f, 0.f};
    f32x4 acc[MT][4];
    #pragma unroll
    for (int i = 0; i < MT; ++i)
        #pragma unroll
        for (int j = 0; j < 4; ++j) acc[i][j] = zero4;
    const int row0 = bm * BM, col0 = bn * 128;
    const size_t ldab = (size_t)lda * 2, ldbb = (size_t)ldb * 2;
    const int lsw = (l16 & 7) * 8;  // fragment-read swizzle (elems)
    for (int k0 = kbeg; k0 < kbeg + Kc; k0 += 64) {
        const char* Abase = (const char*)Ab + (size_t)k0 * 2;
        const char* Bbase = (const char*)Bb + (size_t)k0 * 2;
        #pragma unroll
        for (int p = 0; p < BM / 32; ++p) {
            int o = p * 4096 + tid * 16;         // byte offset into A LDS tile
            int r = o >> 7;                      // row (128 B per row)
            int cs = ((o >> 4) ^ r) & 7;         // swizzled source chunk
            GL2LDS(Abase + (size_t)(row0 + r) * ldab + cs * 16, (char*)smem + o);
        }
        #pragma unroll
        for (int p = 0; p < 4; ++p) {
            int o = p * 4096 + tid * 16;
            int r = o >> 7;
            int cs = ((o >> 4) ^ r) & 7;
            GL2LDS(Bbase + (size_t)(col0 + r) * ldbb + cs * 16, (char*)smem + BM * 128 + o);
        }
        __syncthreads();
        #pragma unroll
        for (int ks = 0; ks < 2; ++ks) {
            u16x8 af[MT], bfr[4];
            #pragma unroll
            for (int t = 0; t < MT; ++t)
                af[t] = *(const u16x8*)&Asub[wm * (BM / 2) + t * 16 + l16][(ks * 32 + quad * 8) ^ lsw];
            #pragma unroll
            for (int t = 0; t < 4; ++t)
                bfr[t] = *(const u16x8*)&Bsub[wn * 64 + t * 16 + l16][(ks * 32 + quad * 8) ^ lsw];
            #pragma unroll
            for (int tm = 0; tm < MT; ++tm)
                #pragma unroll
                for (int tn = 0; tn < 4; ++tn) acc[tm][tn] = mma16<DT>(af[tm], bfr[tn], acc[tm][tn]);
        }
        __syncthreads();
    }

    if constexpr (OUTT == 2) {
        // scalar fp32 epilogue (final projection: bias + residual + fp32 out)
        #pragma unroll
        for (int tm = 0; tm < MT; ++tm)
            #pragma unroll
            for (int tn = 0; tn < 4; ++tn)
                #pragma unroll
                for (int r = 0; r < 4; ++r) {
                    int row = row0 + wm * (BM / 2) + tm * 16 + quad * 4 + r;
                    int col = col0 + wn * 64 + tn * 16 + l16;
                    float v = acc[tm][tn][r];
                    if constexpr (BIAS == 1) v += bias[row];
                    else if constexpr (BIAS == 2) v += bias[col];
                    if constexpr (RESID) v += resid[(size_t)bt * Rs + (size_t)row * N + col];
                    ((float*)outv)[(size_t)zz * Os + (size_t)row * N + col] = v;
                }
    } else {
        // ---- LDS-transpose epilogue (2-byte outputs) ----
        #pragma unroll
        for (int tn = 0; tn < 4; ++tn) {
            int colL = wn * 64 + tn * 16 + l16;
            float bc = 0.f;
            if constexpr (BIAS == 2) bc = bias[col0 + colL];
            else if constexpr (BIAS == 3) {
                int col = col0 + colL;
                bc = (col < 512) ? bias[col] : bias2[col - 512];
            }
            #pragma unroll
            for (int tm = 0; tm < MT; ++tm)
                #pragma unroll
                for (int r = 0; r < 4; ++r) {
                    int rowL = wm * (BM / 2) + tm * 16 + quad * 4 + r;
                    float v = acc[tm][tn][r];
                    if constexpr (BIAS == 1) v += bias[row0 + rowL];
                    else if constexpr (BIAS == 2) v += bc;
                    else if constexpr (BIAS == 3) {
                        int col = col0 + colL;
                        v = (col < 512) ? (v + bc) * SCALE : v + bc;
                    }
                    if constexpr (EXPSUM) v = __expf(v);
                    unsigned short hv;
                    if constexpr (OUTT == 1) { _Float16 h = (_Float16)v; hv = __builtin_bit_cast(unsigned short, h); }
                    else { bf16 h = __float2bfloat16(v); hv = __builtin_bit_cast(unsigned short, h); }
                    smem[rowL * EPITCH + colL] = hv;
                }
        }
        __syncthreads();
        // read phase: chunk = tid&15 (8 cols), rows (tid>>4)*(BM/16) + i; 16B coalesced stores
        const int cch = (tid & 15) * 8;
        const int rg  = (tid >> 4) * (BM / 16);
        #pragma unroll
        for (int i = 0; i < BM / 16; ++i) {
            int rowL = rg + i;
            u16x8 hv = *(const u16x8*)&smem[rowL * EPITCH + cch];
            *(u16x8*)((unsigned short*)outv + (size_t)zz * Os + (size_t)(row0 + rowL) * N + col0 + cch) = hv;
            if constexpr (EXPSUM) {
                float ps = 0.f;
                #pragma unroll
                for (int e = 0; e < 8; ++e) {
                    bf16 h = __builtin_bit_cast(bf16, hv[e]);
                    ps += __bfloat162float(h);
                }
                #pragma unroll
                for (int m = 1; m < 16; m <<= 1) ps += __shfl_xor(ps, m);
                if ((lane & 15) == 0) atomicAdd(lsum + (size_t)bt * Nsp + row0 + rowL, ps);
            }
        }
    }
}

// ---------------------------------------------------------------- fused attention v4 (verified best, r8/r11/r13):
// half-Q-hoist + ring-3. qa[2][8] (64 VGPR) holds Q-d-lo; Q-d-hi resident in LDS (32 KB).
// Ring-3 of 32KB slots + Qhi + P = 136 KB, counted vmcnt(4) per phase (one half always in flight).
// Slots rotate (A,B,C) <- (B,C,A) per tile: S0 consumes A(K-d0) stages V0->C; S1 consumes B(K-d1)+Qhi
// stages V1->A; PV0 consumes C(V-c0) stages K0(t+1)->B (+exp/P mid-barrier); PV1 consumes A(V-c1)
// stages K1(t+1)->C. vmcnt(0) only at the last tile. LDS reads/tile/wave: 52.
// SETTLED LAWS (r9/r10/r12): (1) arch-VGPR envelope ~128 — full-Q-hoist and AGPR-anchored Q both
// spill (WRITE 17->44 MB); (2) barriers are cheap, PREFETCH DISTANCE is not — merging S0+S1 (r12)
// cut a barrier but halved V1's prefetch cover and cost 6us. Do not change the phase structure.
__global__ __launch_bounds__(512, 2) void k_attn(const bf16* __restrict__ QKt_, const bf16* __restrict__ Vm_,
                                                 float* __restrict__ lsum, bf16* __restrict__ Opart_) {
    constexpr int NT = 32;
    const int bx = blockIdx.x, js = blockIdx.y, bt = blockIdx.z;
    const int i0 = bx * 64;
    const int jbase = js * 2048;
    const unsigned short* Qb = (const unsigned short*)QKt_ + (size_t)bt * ((size_t)Nsp * 1024);
    const unsigned short* Vb = (const unsigned short*)Vm_ + (size_t)bt * ((size_t)Nsp * Cdim);  // [c][j] ld 4096
    const int tid = threadIdx.x, lane = tid & 63, w = tid >> 6;
    const int quad = lane >> 4, l16 = lane & 15;
    const int wm = w >> 2, wn = w & 3;   // 2 m-waves x 4 n-waves
    const int lsw = (l16 & 7) * 8;
    __shared__ __align__(16) unsigned short smem[69632];   // ring 3x16384 | Qhi 16384 | P 4096 (139264 B)
    unsigned short* Qhi = smem + 49152;
    unsigned short* P_l = smem + 65536;

    auto stgK = [&](int jj, int dh, unsigned short* dst) {
        #pragma unroll
        for (int s = 0; s < 4; ++s)
            STG1(dst + s * 4096, Qb + (size_t)jj * 1024 + 512 + dh * 256 + s * 64, 1024);
    };
    auto stgV = [&](int jj, int ch, unsigned short* dst) {
        #pragma unroll
        for (int s = 0; s < 4; ++s)
            STG1(dst + s * 4096, Vb + (size_t)(ch * 256 + s * 64) * 4096 + jj, 4096);
    };

#define FRD(base, row, kc) (*(const u16x8*)&(base)[(row) * 64 + ((kc) ^ lsw)])
#define WAIT_BAR(N) \
    asm volatile("s_waitcnt vmcnt(" #N ")" ::: "memory"); \
    __builtin_amdgcn_s_barrier(); \
    __builtin_amdgcn_sched_barrier(0);

    f32x4 zero4 = {0.f, 0.f, 0.f, 0.f};
    f32x4 acc[2][8];
    #pragma unroll
    for (int m = 0; m < 2; ++m)
        #pragma unroll
        for (int n = 0; n < 8; ++n) acc[m][n] = zero4;
    float rsum[2][4] = {{0.f, 0.f, 0.f, 0.f}, {0.f, 0.f, 0.f, 0.f}};
    u16x8 pa[2][2];

    unsigned short* A = smem;            // tile-0: K-d0 slot
    unsigned short* B = smem + 16384;    // tile-0: K-d1 slot
    unsigned short* C = smem + 32768;    // tile-0: V-c0 slot (Q-lo temp in prologue)

    // ---- prologue: Q-lo -> C (temp), Q-hi -> Qhi, K0(0)->A, K1(0)->B ----
    #pragma unroll
    for (int s = 0; s < 4; ++s) STG1(C + s * 4096, Qb + (size_t)i0 * 1024 + s * 64, 1024);
    #pragma unroll
    for (int s = 0; s < 4; ++s) STG1(Qhi + s * 4096, Qb + (size_t)i0 * 1024 + 256 + s * 64, 1024);
    stgK(jbase, 0, A);
    stgK(jbase, 1, B);
    WAIT_BAR(8)                          // Q-lo/Q-hi landed; K halves may be in flight
    u16x8 qa[2][8];                      // Q-d-lo in registers (64 VGPR)
    #pragma unroll
    for (int m = 0; m < 2; ++m)
        #pragma unroll
        for (int ks = 0; ks < 8; ++ks)
            qa[m][ks] = FRD(C + (ks >> 1) * 4096, wm * 32 + m * 16 + l16, (ks & 1) * 32 + quad * 8);
    asm volatile("s_waitcnt lgkmcnt(0)" ::: "memory");
    __builtin_amdgcn_s_barrier();        // C free for V0(0)
    __builtin_amdgcn_sched_barrier(0);

    for (int t = 0; t < NT; ++t) {
        const int j0 = jbase + t * 64;
        const int j1 = j0 + 64;
        f32x4 aS[2] = {zero4, zero4};
        // ---- S0: consume A = K-d0(t); stage V0(t)->C ----
        WAIT_BAR(4)
        stgV(j0, 0, C);
        {
            u16x8 kb[8];
            #pragma unroll
            for (int ks = 0; ks < 8; ++ks)
                kb[ks] = FRD(A + (ks >> 1) * 4096, wn * 16 + l16, (ks & 1) * 32 + quad * 8);
            asm volatile("s_waitcnt lgkmcnt(0)" ::: "memory");
            __builtin_amdgcn_sched_barrier(0);
            __builtin_amdgcn_s_setprio(1);
            #pragma unroll
            for (int ks = 0; ks < 8; ++ks)
                #pragma unroll
                for (int m = 0; m < 2; ++m) aS[m] = mma16<0>(qa[m][ks], kb[ks], aS[m]);
            __builtin_amdgcn_s_setprio(0);
        }
        // ---- S1: consume B = K-d1(t) + Q-hi from LDS; stage V1(t)->A ----
        WAIT_BAR(4)
        stgV(j0, 1, A);
        {
            u16x8 kb[8];
            #pragma unroll
            for (int ks = 0; ks < 8; ++ks)
                kb[ks] = FRD(B + (ks >> 1) * 4096, wn * 16 + l16, (ks & 1) * 32 + quad * 8);
            asm volatile("s_waitcnt lgkmcnt(0)" ::: "memory");
            __builtin_amdgcn_sched_barrier(0);
            __builtin_amdgcn_s_setprio(1);
            #pragma unroll
            for (int ks = 0; ks < 8; ++ks)
                #pragma unroll
                for (int m = 0; m < 2; ++m) {
                    u16x8 aq = FRD(Qhi + (ks >> 1) * 4096, wm * 32 + m * 16 + l16, (ks & 1) * 32 + quad * 8);
                    aS[m] = mma16<0>(aq, kb[ks], aS[m]);
                }
            __builtin_amdgcn_s_setprio(0);
        }
        // ---- PV0: consume C = V-c0(t); stage K0(t+1)->B; exp + P (mid-barrier) ----
        WAIT_BAR(4)
        if (t + 1 < NT) stgK(j1, 0, B);
        #pragma unroll
        for (int m = 0; m < 2; ++m)
            #pragma unroll
            for (int r = 0; r < 4; ++r) {
                float p = __expf(aS[m][r]);
                rsum[m][r] += p;
                int il = wm * 32 + m * 16 + quad * 4 + r;
                bf16 h = __float2bfloat16(p);
                P_l[il * 64 + ((wn * 16 + l16) ^ ((il & 7) * 8))] = __builtin_bit_cast(unsigned short, h);
            }
        asm volatile("s_waitcnt lgkmcnt(0)" ::: "memory");  // P writes retired
        __builtin_amdgcn_s_barrier();                       // P visible to all waves
        __builtin_amdgcn_sched_barrier(0);
        {
            u16x8 fb[4][2];
            #pragma unroll
            for (int nn = 0; nn < 4; ++nn)
                #pragma unroll
                for (int ks = 0; ks < 2; ++ks)
                    fb[nn][ks] = FRD(C + wn * 4096, nn * 16 + l16, ks * 32 + quad * 8);
            #pragma unroll
            for (int m = 0; m < 2; ++m)
                #pragma unroll
                for (int ks = 0; ks < 2; ++ks)
                    pa[m][ks] = *(const u16x8*)&P_l[(wm * 32 + m * 16 + l16) * 64 + ((ks * 32 + quad * 8) ^ lsw)];
            asm volatile("s_waitcnt lgkmcnt(0)" ::: "memory");
            __builtin_amdgcn_sched_barrier(0);
            __builtin_amdgcn_s_setprio(1);
            #pragma unroll
            for (int m = 0; m < 2; ++m)
                #pragma unroll
                for (int nn = 0; nn < 4; ++nn)
                    #pragma unroll
                    for (int ks = 0; ks < 2; ++ks)
                        acc[m][nn] = mma16<0>(pa[m][ks], fb[nn][ks], acc[m][nn]);
            __builtin_amdgcn_s_setprio(0);
        }
        // ---- PV1: consume A = V-c1(t); stage K1(t+1)->C ----
        if (t + 1 < NT) { WAIT_BAR(4) } else { WAIT_BAR(0) }
        if (t + 1 < NT) stgK(j1, 1, C);
        {
            u16x8 fb[4][2];
            #pragma unroll
            for (int nn = 0; nn < 4; ++nn)
                #pragma unroll
                for (int ks = 0; ks < 2; ++ks)
                    fb[nn][ks] = FRD(A + wn * 4096, nn * 16 + l16, ks * 32 + quad * 8);
            asm volatile("s_waitcnt lgkmcnt(0)" ::: "memory");
            __builtin_amdgcn_sched_barrier(0);
            __builtin_amdgcn_s_setprio(1);
            #pragma unroll
            for (int m = 0; m < 2; ++m)
                #pragma unroll
                for (int nn = 0; nn < 4; ++nn)
                    #pragma unroll
                    for (int ks = 0; ks < 2; ++ks)
                        acc[m][4 + nn] = mma16<0>(pa[m][ks], fb[nn][ks], acc[m][4 + nn]);
            __builtin_amdgcn_s_setprio(0);
        }
        // rotate ring: next tile's (K0,K1,V0) slots
        unsigned short* tmp = A; A = B; B = C; C = tmp;
    }
#undef FRD
#undef WAIT_BAR

    // ---- lsum: per-lane partials -> row sums -> global atomics (j-split blocks both add) ----
    #pragma unroll
    for (int m = 0; m < 2; ++m)
        #pragma unroll
        for (int r = 0; r < 4; ++r) {
            float v = rsum[m][r];
            v += __shfl_xor(v, 1); v += __shfl_xor(v, 2); v += __shfl_xor(v, 4); v += __shfl_xor(v, 8);
            if (l16 == 0)
                atomicAdd(lsum + (size_t)bt * Nsp + i0 + wm * 32 + m * 16 + quad * 4 + r, v);
        }
    __syncthreads();
    // ---- O epilogue: LDS transpose (pitch 520, row&7 XOR) -> 16B coalesced partial stores ----
    #pragma unroll
    for (int m = 0; m < 2; ++m)
        #pragma unroll
        for (int h = 0; h < 2; ++h)
            #pragma unroll
            for (int nn = 0; nn < 4; ++nn) {
                int colL = h * 256 + wn * 64 + nn * 16 + l16;
                int rowB = wm * 32 + m * 16 + quad * 4;
                #pragma unroll
                for (int r = 0; r < 4; ++r) {
                    int rw = rowB + r;
                    bf16 hv = __float2bfloat16(acc[m][h * 4 + nn][r]);
                    smem[rw * 520 + (colL ^ ((rw & 7) * 8))] = __builtin_bit_cast(unsigned short, hv);
                }
            }
    __syncthreads();
    const int orow = tid >> 3, ocb = tid & 7;
    unsigned short* od = (unsigned short*)Opart_ + (size_t)js * ((size_t)NB * Nsp * Cdim) +
                         ((size_t)bt * Nsp + i0 + orow) * Cdim;
    #pragma unroll
    for (int it = 0; it < 8; ++it) {
        int cc = ocb + it * 8;
        u16x8 hv = *(const u16x8*)&smem[orow * 520 + ((cc * 8) ^ ((orow & 7) * 8))];
        *(u16x8*)(od + cc * 8) = hv;
    }
}

// ---------------------------------------------------------------- sum 2 bf16 j-split partials, /l -> bf16
__global__ __launch_bounds__(256) void k_reduce2(const bf16* __restrict__ P, const float* __restrict__ lsum,
                                                 bf16* __restrict__ O) {
    constexpr size_t SL = (size_t)NB * Nsp * Cdim;  // 4194304 elems per slab
    size_t i = ((size_t)blockIdx.x * 256 + threadIdx.x) * 8;
    float linv = 1.f / lsum[i >> 9];  // flat/512 = b*Nsp + row
    union { bf16 h[8]; uint4 u; } a, b, r;
    a.u = *(const uint4*)(P + i);
    b.u = *(const uint4*)(P + SL + i);
    #pragma unroll
    for (int e = 0; e < 8; ++e) {
        float s = __bfloat162float(a.h[e]) + __bfloat162float(b.h[e]);
        r.h[e] = __float2bfloat16(s * linv);
    }
    *(uint4*)(O + i) = r.u;
}

// ---------------------------------------------------------------- launcher
extern "C" void kernel_launch(void* const* d_in, const int* in_sizes, int n_in,
                              void* d_out, int out_size, void* d_ws, size_t ws_size,
                              hipStream_t stream) {
    const float* x     = (const float*)d_in[0];
    const float* gamma = (const float*)d_in[1];
    const float* beta  = (const float*)d_in[2];
    const float* wq = (const float*)d_in[3];  const float* bq = (const float*)d_in[4];
    const float* wk = (const float*)d_in[5];  const float* bk = (const float*)d_in[6];
    const float* wv = (const float*)d_in[7];  const float* bv = (const float*)d_in[8];
    const float* wo = (const float*)d_in[9];  const float* bo = (const float*)d_in[10];
    float* out = (float*)d_out;

    // workspace layout
    char* ws = (char*)d_ws;
    float* stats = (float*)ws;  // 4 KB: 64 bg x 8 sub x {sum, sumsq}
    size_t off = 8192;
    float* lsum = (float*)(ws + off); off += (size_t)NB * Nsp * 4 + 1024;  // 32 KB row sums
    bf16* wqkb = (bf16*)(ws + off); off += (size_t)1024 * 512 * 2;        // 1 MB  [1024][512] Q then K
    bf16* wvb  = (bf16*)(ws + off); off += (size_t)512 * 512 * 2;         // 0.5 MB
    bf16* wob  = (bf16*)(ws + off); off += (size_t)512 * 512 * 2;         // 0.5 MB
    bf16* Vm   = (bf16*)(ws + off); off += (size_t)NB * Nsp * Cdim * 2;   // 8 MB  [b][c][j]
    bf16* Ot   = (bf16*)(ws + off); off += (size_t)NB * Nsp * Cdim * 2;   // 8 MB  [b][i][c]
    bf16* Opart = (bf16*)(ws + off); off += (size_t)2 * NB * Nsp * Cdim * 2;  // 16 MB: 2 j-split slabs
    bf16* ht   = (bf16*)(ws + off); off += (size_t)NB * Nsp * Cdim * 2;   // 8 MB  [b][n][c]
    bf16* QKt  = (bf16*)(ws + off); off += (size_t)NB * Nsp * 1024 * 2;   // 16 MB [b][n][1024]

    // fused: weight cvt (0..255) + lsum zero (256) + GN partial stats (257..768, 512 blocks)
    k_cvt_all<<<769, 256, 0, stream>>>(wq, wk, wv, wo, wqkb, wvb, wob, lsum, x, stats);
    // GN apply: 1024 blocks (n0 x c0 x b), finalizes partials per block
    k_gn_apply<<<dim3(64, 8, 2), 256, 0, stream>>>(x, stats, gamma, beta, ht);

    const long long hs = (long long)Nsp * Cdim;    // 2097152
    const long long qs = (long long)Nsp * 1024;    // 4194304

    // fused Q+K proj: QKt[i][co'] = (sum_k ht[i][k] wqk[co'][k] + b) (*SCALE for Q half)
    k_gemm_nt<128, 0, 0, 3, 0, 1, 0><<<dim3(32, 8, 2), 256, 0, stream>>>(
        ht, hs, 512, wqkb, 0, 512, bq, bk, nullptr, 0, nullptr, QKt, qs, 1024, 512);
    // V: Vm[co][j] = sum_k wv[co][k] ht[j][k] + bv  (M=512, N=4096, bf16 out)
    k_gemm_nt<128, 0, 0, 1, 0, 1, 0><<<dim3(4, 32, 2), 256, 0, stream>>>(
        wvb, 0, 512, ht, hs, 512, bv, nullptr, nullptr, 0, nullptr, Vm, hs, 4096, 512);
    // fused attention: O_partial (2 j-split slabs) + lsum
    k_attn<<<dim3(64, 2, 2), 512, 0, stream>>>(QKt, Vm, lsum, Opart);
    // combine j-split partials, divide by row sums -> Ot bf16
    k_reduce2<<<2048, 256, 0, stream>>>(Opart, lsum, Ot);
    // out[co][i] = x[co][i] + bo[co] + sum_k wo[co][k] Ot[i][k]  (fp32 out + residual)
    k_gemm_nt<128, 0, 2, 1, 1, 1, 0><<<dim3(4, 32, 2), 256, 0, stream>>>(
        wob, 0, 512, Ot, hs, 512, bo, nullptr, x, hs, nullptr, out, hs, 4096, 512);
}

// Round 15
// 210.014 us; speedup vs baseline: 1.1945x; 1.0622x over previous
//
#include <hip/hip_runtime.h>
#include <hip/hip_bf16.h>

typedef __bf16 bf16x8 __attribute__((ext_vector_type(8)));
typedef _Float16 f16x8 __attribute__((ext_vector_type(8)));
typedef unsigned short u16x8 __attribute__((ext_vector_type(8)));
typedef float f32x4 __attribute__((ext_vector_type(4)));
using bf16 = __hip_bfloat16;

constexpr int Cdim = 512;   // channels
constexpr int Nsp  = 4096;  // d*h*w
constexpr int NB   = 2;     // batch
constexpr float SCALE = 0.04419417382415922f;  // 512^-0.5
constexpr int EPITCH = 132; // epilogue LDS pitch (elems) for gemm body

// async 16B global->LDS (m97 pattern). LDS dest must be wave-uniform base + lane*16.
#define GL2LDS(gaddr, laddr)                                                              \
    __builtin_amdgcn_global_load_lds((const __attribute__((address_space(1))) void*)(gaddr), \
                                     (__attribute__((address_space(3))) void*)(laddr), 16, 0, 0)

// stage one 8KB [64 rows][64 elems] bf16 subtile: 1 GL2LDS per thread (512 thd),
// linear LDS dest, XOR-pre-swizzled global source chunk (verified k_gemm_nt pattern).
#define STG1(dst, src, ld) { int _o = tid * 16, _r = _o >> 7, _c = ((_o >> 4) ^ _r) & 7;      \
    GL2LDS((const unsigned short*)(src) + (size_t)_r * (ld) + _c * 8,                          \
           (unsigned short*)(dst) + (_o >> 1)); }

// ---------------------------------------------------------------- weights fp32 -> bf16 + zero lsum + GN partial
// stats, one launch: blocks 0..255 cvt, 256 zero-lsum, 257..768 partial stats (64 bg x 8 sub-blocks).
__global__ __launch_bounds__(256) void k_cvt_all(const float* __restrict__ wq, const float* __restrict__ wk,
                                                 const float* __restrict__ wv, const float* __restrict__ wo,
                                                 bf16* __restrict__ wqkb, bf16* __restrict__ wvb,
                                                 bf16* __restrict__ wob, float* __restrict__ lsum,
                                                 const float* __restrict__ x, float* __restrict__ stats) {
    __shared__ float rs[4], rs2[4];
    if (blockIdx.x >= 257) {  // partial sums: pb = bg*8 + sub
        int pb = blockIdx.x - 257;            // 0..511
        int bg = pb >> 3, sub = pb & 7;
        const float4* p = (const float4*)(x + (size_t)bg * 65536) + sub * 2048;
        float s = 0.f, s2 = 0.f;
        #pragma unroll
        for (int k = 0; k < 8; ++k) {
            float4 v = p[threadIdx.x + k * 256];
            s  += v.x + v.y + v.z + v.w;
            s2 += v.x * v.x + v.y * v.y + v.z * v.z + v.w * v.w;
        }
        #pragma unroll
        for (int off = 32; off; off >>= 1) { s += __shfl_xor(s, off); s2 += __shfl_xor(s2, off); }
        int w = threadIdx.x >> 6;
        if ((threadIdx.x & 63) == 0) { rs[w] = s; rs2[w] = s2; }
        __syncthreads();
        if (threadIdx.x == 0) {
            stats[pb * 2]     = rs[0] + rs[1] + rs[2] + rs[3];
            stats[pb * 2 + 1] = rs2[0] + rs2[1] + rs2[2] + rs2[3];
        }
        return;
    }
    if (blockIdx.x == 256) {  // zero 8192-float lsum
        #pragma unroll
        for (int j = 0; j < 8; ++j)
            ((float4*)lsum)[8 * threadIdx.x + j] = float4{0.f, 0.f, 0.f, 0.f};
        return;
    }
    int i = blockIdx.x * 256 + threadIdx.x;  // 65536 float4 groups per weight
    float4 q = ((const float4*)wq)[i];
    float4 k = ((const float4*)wk)[i];
    float4 v = ((const float4*)wv)[i];
    float4 o = ((const float4*)wo)[i];
    bf16* dq = wqkb + (size_t)i * 4;
    dq[0] = __float2bfloat16(q.x); dq[1] = __float2bfloat16(q.y);
    dq[2] = __float2bfloat16(q.z); dq[3] = __float2bfloat16(q.w);
    bf16* dk = wqkb + 262144 + (size_t)i * 4;
    dk[0] = __float2bfloat16(k.x); dk[1] = __float2bfloat16(k.y);
    dk[2] = __float2bfloat16(k.z); dk[3] = __float2bfloat16(k.w);
    bf16* dv = wvb + (size_t)i * 4;
    dv[0] = __float2bfloat16(v.x); dv[1] = __float2bfloat16(v.y);
    dv[2] = __float2bfloat16(v.z); dv[3] = __float2bfloat16(v.w);
    bf16* dw = wob + (size_t)i * 4;
    dw[0] = __float2bfloat16(o.x); dw[1] = __float2bfloat16(o.y);
    dw[2] = __float2bfloat16(o.z); dw[3] = __float2bfloat16(o.w);
}

// ---------------------------------------------------------------- groupnorm apply + transpose -> ht[b,n,c] bf16
// 1024 blocks — c0 in blockIdx.y; finalizes the 8 partial sums per group.
__global__ __launch_bounds__(256) void k_gn_apply(const float* __restrict__ x, const float* __restrict__ partial,
                                                  const float* __restrict__ gamma, const float* __restrict__ beta,
                                                  bf16* __restrict__ ht) {
    int b = blockIdx.z;
    int c0 = blockIdx.y * 64;
    int n0 = blockIdx.x * 64;
    int tid = threadIdx.x;
    __shared__ float tile[64][65];
    __shared__ float smean[4], srstd[4];
    if (tid < 4) {  // finalize the 4 groups covered by this c0
        int g = (c0 >> 4) + tid;
        const float* pp = partial + (size_t)(b * 32 + g) * 16;
        float S = 0.f, S2 = 0.f;
        #pragma unroll
        for (int k = 0; k < 8; ++k) { S += pp[k * 2]; S2 += pp[k * 2 + 1]; }
        float mean = S * (1.f / 65536.f);
        float var  = S2 * (1.f / 65536.f) - mean * mean;
        smean[tid] = mean;
        srstd[tid] = rsqrtf(var + 1e-6f);
    }
    int nn_l = tid & 63, cc0 = tid >> 6;
    #pragma unroll
    for (int p = 0; p < 16; ++p) {
        int cc = p * 4 + cc0;
        tile[cc][nn_l] = x[(size_t)(b * Cdim + c0 + cc) * Nsp + n0 + nn_l];
    }
    __syncthreads();
    int cc_w = tid & 63, nn0 = tid >> 6;
    int c = c0 + cc_w;
    float mean = smean[cc_w >> 4];
    float rstd = srstd[cc_w >> 4];
    float ga = gamma[c], be = beta[c];
    #pragma unroll
    for (int p = 0; p < 16; ++p) {
        int nn = p * 4 + nn0;
        float v = tile[cc_w][nn];
        ht[(size_t)(b * Nsp + n0 + nn) * Cdim + c] = __float2bfloat16((v - mean) * rstd * ga + be);
    }
}

// ---------------------------------------------------------------- MFMA dtype dispatch
template <int DT>
__device__ __forceinline__ f32x4 mma16(u16x8 a, u16x8 b, f32x4 c) {
    if constexpr (DT == 0)
        return __builtin_amdgcn_mfma_f32_16x16x32_bf16(__builtin_bit_cast(bf16x8, a),
                                                       __builtin_bit_cast(bf16x8, b), c, 0, 0, 0);
    else
        return __builtin_amdgcn_mfma_f32_16x16x32_f16(__builtin_bit_cast(f16x8, a),
                                                      __builtin_bit_cast(f16x8, b), c, 0, 0, 0);
}

// ---------------------------------------------------------------- NT GEMM body (m97 structure, verified) as a
// device function: takes the LDS pointer + block coords so multiple block-uniform paths can share one launch.
// Logic byte-identical to the round-0-verified k_gemm_nt.
constexpr int SME128 = ((128 + 128) * 64 > 128 * EPITCH) ? (128 + 128) * 64 : 128 * EPITCH;  // 16896 ushorts

template <int BM, int DT, int OUTT, int BIAS, int RESID, int SPLITK, int EXPSUM>
__device__ __forceinline__ void gemm_dev(
    unsigned short* smem, int bm, int bn, int zz,
    const void* __restrict__ Av, long long As, int lda,
    const void* __restrict__ Bv, long long Bs, int ldb,
    const float* __restrict__ bias, const float* __restrict__ bias2,
    const float* __restrict__ resid, long long Rs,
    float* __restrict__ lsum,
    void* __restrict__ outv, long long Os,
    int N, int K) {
    constexpr int MT = BM / 32;       // m-tiles per wave
    const int bt  = (SPLITK > 1) ? (zz % NB) : zz;
    const int ksl = (SPLITK > 1) ? (zz / NB) : 0;
    const int Kc = K / SPLITK;
    const int kbeg = ksl * Kc;
    const unsigned short* Ab = (const unsigned short*)Av + (size_t)bt * As;
    const unsigned short* Bb = (const unsigned short*)Bv + (size_t)bt * Bs;
    const int tid = threadIdx.x, lane = tid & 63, w = tid >> 6;
    const int quad = lane >> 4, l16 = lane & 15;
    const int wm = w >> 1, wn = w & 1;
    unsigned short (*Asub)[64] = (unsigned short(*)[64])smem;
    unsigned short (*Bsub)[64] = (unsigned short(*)[64])(smem + BM * 64);
    f32x4 zero4 = {0.f, 0.f, 0.f, 0.f};
    f32x4 acc[MT][4];
    #pragma unroll
    for (int i = 0; i < MT; ++i)
        #pragma unroll
        for (int j = 0; j < 4; ++j) acc[i][j] = zero4;
    const int row0 = bm * BM, col0 = bn * 128;
    const size_t ldab = (size_t)lda * 2, ldbb = (size_t)ldb * 2;
    const int lsw = (l16 & 7) * 8;  // fragment-read swizzle (elems)
    for (int k0 = kbeg; k0 < kbeg + Kc; k0 += 64) {
        const char* Abase = (const char*)Ab + (size_t)k0 * 2;
        const char* Bbase = (const char*)Bb + (size_t)k0 * 2;
        #pragma unroll
        for (int p = 0; p < BM / 32; ++p) {
            int o = p * 4096 + tid * 16;         // byte offset into A LDS tile
            int r = o >> 7;                      // row (128 B per row)
            int cs = ((o >> 4) ^ r) & 7;         // swizzled source chunk
            GL2LDS(Abase + (size_t)(row0 + r) * ldab + cs * 16, (char*)smem + o);
        }
        #pragma unroll
        for (int p = 0; p < 4; ++p) {
            int o = p * 4096 + tid * 16;
            int r = o >> 7;
            int cs = ((o >> 4) ^ r) & 7;
            GL2LDS(Bbase + (size_t)(col0 + r) * ldbb + cs * 16, (char*)smem + BM * 128 + o);
        }
        __syncthreads();
        #pragma unroll
        for (int ks = 0; ks < 2; ++ks) {
            u16x8 af[MT], bfr[4];
            #pragma unroll
            for (int t = 0; t < MT; ++t)
                af[t] = *(const u16x8*)&Asub[wm * (BM / 2) + t * 16 + l16][(ks * 32 + quad * 8) ^ lsw];
            #pragma unroll
            for (int t = 0; t < 4; ++t)
                bfr[t] = *(const u16x8*)&Bsub[wn * 64 + t * 16 + l16][(ks * 32 + quad * 8) ^ lsw];
            #pragma unroll
            for (int tm = 0; tm < MT; ++tm)
                #pragma unroll
                for (int tn = 0; tn < 4; ++tn) acc[tm][tn] = mma16<DT>(af[tm], bfr[tn], acc[tm][tn]);
        }
        __syncthreads();
    }

    if constexpr (OUTT == 2) {
        // scalar fp32 epilogue (final projection: bias + residual + fp32 out)
        #pragma unroll
        for (int tm = 0; tm < MT; ++tm)
            #pragma unroll
            for (int tn = 0; tn < 4; ++tn)
                #pragma unroll
                for (int r = 0; r < 4; ++r) {
                    int row = row0 + wm * (BM / 2) + tm * 16 + quad * 4 + r;
                    int col = col0 + wn * 64 + tn * 16 + l16;
                    float v = acc[tm][tn][r];
                    if constexpr (BIAS == 1) v += bias[row];
                    else if constexpr (BIAS == 2) v += bias[col];
                    if constexpr (RESID) v += resid[(size_t)bt * Rs + (size_t)row * N + col];
                    ((float*)outv)[(size_t)zz * Os + (size_t)row * N + col] = v;
                }
    } else {
        // ---- LDS-transpose epilogue (2-byte outputs) ----
        #pragma unroll
        for (int tn = 0; tn < 4; ++tn) {
            int colL = wn * 64 + tn * 16 + l16;
            float bc = 0.f;
            if constexpr (BIAS == 2) bc = bias[col0 + colL];
            else if constexpr (BIAS == 3) {
                int col = col0 + colL;
                bc = (col < 512) ? bias[col] : bias2[col - 512];
            }
            #pragma unroll
            for (int tm = 0; tm < MT; ++tm)
                #pragma unroll
                for (int r = 0; r < 4; ++r) {
                    int rowL = wm * (BM / 2) + tm * 16 + quad * 4 + r;
                    float v = acc[tm][tn][r];
                    if constexpr (BIAS == 1) v += bias[row0 + rowL];
                    else if constexpr (BIAS == 2) v += bc;
                    else if constexpr (BIAS == 3) {
                        int col = col0 + colL;
                        v = (col < 512) ? (v + bc) * SCALE : v + bc;
                    }
                    if constexpr (EXPSUM) v = __expf(v);
                    unsigned short hv;
                    if constexpr (OUTT == 1) { _Float16 h = (_Float16)v; hv = __builtin_bit_cast(unsigned short, h); }
                    else { bf16 h = __float2bfloat16(v); hv = __builtin_bit_cast(unsigned short, h); }
                    smem[rowL * EPITCH + colL] = hv;
                }
        }
        __syncthreads();
        // read phase: chunk = tid&15 (8 cols), rows (tid>>4)*(BM/16) + i; 16B coalesced stores
        const int cch = (tid & 15) * 8;
        const int rg  = (tid >> 4) * (BM / 16);
        #pragma unroll
        for (int i = 0; i < BM / 16; ++i) {
            int rowL = rg + i;
            u16x8 hv = *(const u16x8*)&smem[rowL * EPITCH + cch];
            *(u16x8*)((unsigned short*)outv + (size_t)zz * Os + (size_t)(row0 + rowL) * N + col0 + cch) = hv;
            if constexpr (EXPSUM) {
                float ps = 0.f;
                #pragma unroll
                for (int e = 0; e < 8; ++e) {
                    bf16 h = __builtin_bit_cast(bf16, hv[e]);
                    ps += __bfloat162float(h);
                }
                #pragma unroll
                for (int m = 1; m < 16; m <<= 1) ps += __shfl_xor(ps, m);
                if ((lane & 15) == 0) atomicAdd(lsum + (size_t)bt * Nsp + row0 + rowL, ps);
            }
        }
    }
}

// thin wrapper: identical behavior to the old k_gemm_nt (used for O-proj)
template <int BM, int DT, int OUTT, int BIAS, int RESID, int SPLITK, int EXPSUM>
__global__ __launch_bounds__(256) void k_gemm_nt(
    const void* __restrict__ Av, long long As, int lda,
    const void* __restrict__ Bv, long long Bs, int ldb,
    const float* __restrict__ bias, const float* __restrict__ bias2,
    const float* __restrict__ resid, long long Rs,
    float* __restrict__ lsum,
    void* __restrict__ outv, long long Os,
    int N, int K) {
    __shared__ __align__(16) unsigned short smem[SME128];
    gemm_dev<BM, DT, OUTT, BIAS, RESID, SPLITK, EXPSUM>(
        smem, blockIdx.x, blockIdx.y, blockIdx.z,
        Av, As, lda, Bv, Bs, ldb, bias, bias2, resid, Rs, lsum, outv, Os, N, K);
}

// merged QK-proj + V-proj (independent, both read ht): z<2 -> QK (bm=x,bn=y,bt=z);
// z==2 -> V with (bm,bn,bt) decoded from the 32x8 flat index. One launch, 768 blocks = 3/CU.
__global__ __launch_bounds__(256) void k_gemm_qkv(
    const bf16* __restrict__ ht, const bf16* __restrict__ wqkb, const bf16* __restrict__ wvb,
    const float* __restrict__ bq, const float* __restrict__ bk, const float* __restrict__ bv,
    bf16* __restrict__ QKt, bf16* __restrict__ Vm) {
    __shared__ __align__(16) unsigned short smem[SME128];
    const long long hs = (long long)Nsp * Cdim;
    const long long qs = (long long)Nsp * 1024;
    if (blockIdx.z < 2) {
        // QKt[i][co'] = (sum_k ht[i][k] wqk[co'][k] + b) (*SCALE for Q half); M=4096, N=1024, K=512
        gemm_dev<128, 0, 0, 3, 0, 1, 0>(smem, blockIdx.x, blockIdx.y, blockIdx.z,
                                        ht, hs, 512, wqkb, 0, 512, bq, bk, nullptr, 0, nullptr,
                                        QKt, qs, 1024, 512);
    } else {
        // Vm[co][j] = sum_k wv[co][k] ht[j][k] + bv; M=512, N=4096, K=512 (grid 4x32x2 from 32x8 flat)
        int flat = blockIdx.y * 32 + blockIdx.x;       // 0..255
        int bm = flat & 3, bn = (flat >> 2) & 31, bt = flat >> 7;
        gemm_dev<128, 0, 0, 1, 0, 1, 0>(smem, bm, bn, bt,
                                        wvb, 0, 512, ht, hs, 512, bv, nullptr, nullptr, 0, nullptr,
                                        Vm, hs, 4096, 512);
    }
}

// ---------------------------------------------------------------- fused attention v4 (verified best, r8/r11/r13):
// half-Q-hoist + ring-3. qa[2][8] (64 VGPR) holds Q-d-lo; Q-d-hi resident in LDS (32 KB).
// Ring-3 of 32KB slots + Qhi + P = 136 KB, counted vmcnt(4) per phase (one half always in flight).
// SETTLED LAWS (r9/r10/r12): (1) arch-VGPR envelope ~128 — persistent register additions spill;
// (2) barriers are cheap, PREFETCH DISTANCE is not — do not change the phase structure.
__global__ __launch_bounds__(512, 2) void k_attn(const bf16* __restrict__ QKt_, const bf16* __restrict__ Vm_,
                                                 float* __restrict__ lsum, bf16* __restrict__ Opart_) {
    constexpr int NT = 32;
    const int bx = blockIdx.x, js = blockIdx.y, bt = blockIdx.z;
    const int i0 = bx * 64;
    const int jbase = js * 2048;
    const unsigned short* Qb = (const unsigned short*)QKt_ + (size_t)bt * ((size_t)Nsp * 1024);
    const unsigned short* Vb = (const unsigned short*)Vm_ + (size_t)bt * ((size_t)Nsp * Cdim);  // [c][j] ld 4096
    const int tid = threadIdx.x, lane = tid & 63, w = tid >> 6;
    const int quad = lane >> 4, l16 = lane & 15;
    const int wm = w >> 2, wn = w & 3;   // 2 m-waves x 4 n-waves
    const int lsw = (l16 & 7) * 8;
    __shared__ __align__(16) unsigned short smem[69632];   // ring 3x16384 | Qhi 16384 | P 4096 (139264 B)
    unsigned short* Qhi = smem + 49152;
    unsigned short* P_l = smem + 65536;

    auto stgK = [&](int jj, int dh, unsigned short* dst) {
        #pragma unroll
        for (int s = 0; s < 4; ++s)
            STG1(dst + s * 4096, Qb + (size_t)jj * 1024 + 512 + dh * 256 + s * 64, 1024);
    };
    auto stgV = [&](int jj, int ch, unsigned short* dst) {
        #pragma unroll
        for (int s = 0; s < 4; ++s)
            STG1(dst + s * 4096, Vb + (size_t)(ch * 256 + s * 64) * 4096 + jj, 4096);
    };

#define FRD(base, row, kc) (*(const u16x8*)&(base)[(row) * 64 + ((kc) ^ lsw)])
#define WAIT_BAR(N) \
    asm volatile("s_waitcnt vmcnt(" #N ")" ::: "memory"); \
    __builtin_amdgcn_s_barrier(); \
    __builtin_amdgcn_sched_barrier(0);

    f32x4 zero4 = {0.f, 0.f, 0.f, 0.f};
    f32x4 acc[2][8];
    #pragma unroll
    for (int m = 0; m < 2; ++m)
        #pragma unroll
        for (int n = 0; n < 8; ++n) acc[m][n] = zero4;
    float rsum[2][4] = {{0.f, 0.f, 0.f, 0.f}, {0.f, 0.f, 0.f, 0.f}};
    u16x8 pa[2][2];

    unsigned short* A = smem;            // tile-0: K-d0 slot
    unsigned short* B = smem + 16384;    // tile-0: K-d1 slot
    unsigned short* C = smem + 32768;    // tile-0: V-c0 slot (Q-lo temp in prologue)

    // ---- prologue: Q-lo -> C (temp), Q-hi -> Qhi, K0(0)->A, K1(0)->B ----
    #pragma unroll
    for (int s = 0; s < 4; ++s) STG1(C + s * 4096, Qb + (size_t)i0 * 1024 + s * 64, 1024);
    #pragma unroll
    for (int s = 0; s < 4; ++s) STG1(Qhi + s * 4096, Qb + (size_t)i0 * 1024 + 256 + s * 64, 1024);
    stgK(jbase, 0, A);
    stgK(jbase, 1, B);
    WAIT_BAR(8)                          // Q-lo/Q-hi landed; K halves may be in flight
    u16x8 qa[2][8];                      // Q-d-lo in registers (64 VGPR)
    #pragma unroll
    for (int m = 0; m < 2; ++m)
        #pragma unroll
        for (int ks = 0; ks < 8; ++ks)
            qa[m][ks] = FRD(C + (ks >> 1) * 4096, wm * 32 + m * 16 + l16, (ks & 1) * 32 + quad * 8);
    asm volatile("s_waitcnt lgkmcnt(0)" ::: "memory");
    __builtin_amdgcn_s_barrier();        // C free for V0(0)
    __builtin_amdgcn_sched_barrier(0);

    for (int t = 0; t < NT; ++t) {
        const int j0 = jbase + t * 64;
        const int j1 = j0 + 64;
        f32x4 aS[2] = {zero4, zero4};
        // ---- S0: consume A = K-d0(t); stage V0(t)->C ----
        WAIT_BAR(4)
        stgV(j0, 0, C);
        {
            u16x8 kb[8];
            #pragma unroll
            for (int ks = 0; ks < 8; ++ks)
                kb[ks] = FRD(A + (ks >> 1) * 4096, wn * 16 + l16, (ks & 1) * 32 + quad * 8);
            asm volatile("s_waitcnt lgkmcnt(0)" ::: "memory");
            __builtin_amdgcn_sched_barrier(0);
            __builtin_amdgcn_s_setprio(1);
            #pragma unroll
            for (int ks = 0; ks < 8; ++ks)
                #pragma unroll
                for (int m = 0; m < 2; ++m) aS[m] = mma16<0>(qa[m][ks], kb[ks], aS[m]);
            __builtin_amdgcn_s_setprio(0);
        }
        // ---- S1: consume B = K-d1(t) + Q-hi from LDS; stage V1(t)->A ----
        WAIT_BAR(4)
        stgV(j0, 1, A);
        {
            u16x8 kb[8];
            #pragma unroll
            for (int ks = 0; ks < 8; ++ks)
                kb[ks] = FRD(B + (ks >> 1) * 4096, wn * 16 + l16, (ks & 1) * 32 + quad * 8);
            asm volatile("s_waitcnt lgkmcnt(0)" ::: "memory");
            __builtin_amdgcn_sched_barrier(0);
            __builtin_amdgcn_s_setprio(1);
            #pragma unroll
            for (int ks = 0; ks < 8; ++ks)
                #pragma unroll
                for (int m = 0; m < 2; ++m) {
                    u16x8 aq = FRD(Qhi + (ks >> 1) * 4096, wm * 32 + m * 16 + l16, (ks & 1) * 32 + quad * 8);
                    aS[m] = mma16<0>(aq, kb[ks], aS[m]);
                }
            __builtin_amdgcn_s_setprio(0);
        }
        // ---- PV0: consume C = V-c0(t); stage K0(t+1)->B; exp + P (mid-barrier) ----
        WAIT_BAR(4)
        if (t + 1 < NT) stgK(j1, 0, B);
        #pragma unroll
        for (int m = 0; m < 2; ++m)
            #pragma unroll
            for (int r = 0; r < 4; ++r) {
                float p = __expf(aS[m][r]);
                rsum[m][r] += p;
                int il = wm * 32 + m * 16 + quad * 4 + r;
                bf16 h = __float2bfloat16(p);
                P_l[il * 64 + ((wn * 16 + l16) ^ ((il & 7) * 8))] = __builtin_bit_cast(unsigned short, h);
            }
        asm volatile("s_waitcnt lgkmcnt(0)" ::: "memory");  // P writes retired
        __builtin_amdgcn_s_barrier();                       // P visible to all waves
        __builtin_amdgcn_sched_barrier(0);
        {
            u16x8 fb[4][2];
            #pragma unroll
            for (int nn = 0; nn < 4; ++nn)
                #pragma unroll
                for (int ks = 0; ks < 2; ++ks)
                    fb[nn][ks] = FRD(C + wn * 4096, nn * 16 + l16, ks * 32 + quad * 8);
            #pragma unroll
            for (int m = 0; m < 2; ++m)
                #pragma unroll
                for (int ks = 0; ks < 2; ++ks)
                    pa[m][ks] = *(const u16x8*)&P_l[(wm * 32 + m * 16 + l16) * 64 + ((ks * 32 + quad * 8) ^ lsw)];
            asm volatile("s_waitcnt lgkmcnt(0)" ::: "memory");
            __builtin_amdgcn_sched_barrier(0);
            __builtin_amdgcn_s_setprio(1);
            #pragma unroll
            for (int m = 0; m < 2; ++m)
                #pragma unroll
                for (int nn = 0; nn < 4; ++nn)
                    #pragma unroll
                    for (int ks = 0; ks < 2; ++ks)
                        acc[m][nn] = mma16<0>(pa[m][ks], fb[nn][ks], acc[m][nn]);
            __builtin_amdgcn_s_setprio(0);
        }
        // ---- PV1: consume A = V-c1(t); stage K1(t+1)->C ----
        if (t + 1 < NT) { WAIT_BAR(4) } else { WAIT_BAR(0) }
        if (t + 1 < NT) stgK(j1, 1, C);
        {
            u16x8 fb[4][2];
            #pragma unroll
            for (int nn = 0; nn < 4; ++nn)
                #pragma unroll
                for (int ks = 0; ks < 2; ++ks)
                    fb[nn][ks] = FRD(A + wn * 4096, nn * 16 + l16, ks * 32 + quad * 8);
            asm volatile("s_waitcnt lgkmcnt(0)" ::: "memory");
            __builtin_amdgcn_sched_barrier(0);
            __builtin_amdgcn_s_setprio(1);
            #pragma unroll
            for (int m = 0; m < 2; ++m)
                #pragma unroll
                for (int nn = 0; nn < 4; ++nn)
                    #pragma unroll
                    for (int ks = 0; ks < 2; ++ks)
                        acc[m][4 + nn] = mma16<0>(pa[m][ks], fb[nn][ks], acc[m][4 + nn]);
            __builtin_amdgcn_s_setprio(0);
        }
        // rotate ring: next tile's (K0,K1,V0) slots
        unsigned short* tmp = A; A = B; B = C; C = tmp;
    }
#undef FRD
#undef WAIT_BAR

    // ---- lsum: per-lane partials -> row sums -> global atomics (j-split blocks both add) ----
    #pragma unroll
    for (int m = 0; m < 2; ++m)
        #pragma unroll
        for (int r = 0; r < 4; ++r) {
            float v = rsum[m][r];
            v += __shfl_xor(v, 1); v += __shfl_xor(v, 2); v += __shfl_xor(v, 4); v += __shfl_xor(v, 8);
            if (l16 == 0)
                atomicAdd(lsum + (size_t)bt * Nsp + i0 + wm * 32 + m * 16 + quad * 4 + r, v);
        }
    __syncthreads();
    // ---- O epilogue: LDS transpose (pitch 520, row&7 XOR) -> 16B coalesced partial stores ----
    #pragma unroll
    for (int m = 0; m < 2; ++m)
        #pragma unroll
        for (int h = 0; h < 2; ++h)
            #pragma unroll
            for (int nn = 0; nn < 4; ++nn) {
                int colL = h * 256 + wn * 64 + nn * 16 + l16;
                int rowB = wm * 32 + m * 16 + quad * 4;
                #pragma unroll
                for (int r = 0; r < 4; ++r) {
                    int rw = rowB + r;
                    bf16 hv = __float2bfloat16(acc[m][h * 4 + nn][r]);
                    smem[rw * 520 + (colL ^ ((rw & 7) * 8))] = __builtin_bit_cast(unsigned short, hv);
                }
            }
    __syncthreads();
    const int orow = tid >> 3, ocb = tid & 7;
    unsigned short* od = (unsigned short*)Opart_ + (size_t)js * ((size_t)NB * Nsp * Cdim) +
                         ((size_t)bt * Nsp + i0 + orow) * Cdim;
    #pragma unroll
    for (int it = 0; it < 8; ++it) {
        int cc = ocb + it * 8;
        u16x8 hv = *(const u16x8*)&smem[orow * 520 + ((cc * 8) ^ ((orow & 7) * 8))];
        *(u16x8*)(od + cc * 8) = hv;
    }
}

// ---------------------------------------------------------------- sum 2 bf16 j-split partials, /l -> bf16
__global__ __launch_bounds__(256) void k_reduce2(const bf16* __restrict__ P, const float* __restrict__ lsum,
                                                 bf16* __restrict__ O) {
    constexpr size_t SL = (size_t)NB * Nsp * Cdim;  // 4194304 elems per slab
    size_t i = ((size_t)blockIdx.x * 256 + threadIdx.x) * 8;
    float linv = 1.f / lsum[i >> 9];  // flat/512 = b*Nsp + row
    union { bf16 h[8]; uint4 u; } a, b, r;
    a.u = *(const uint4*)(P + i);
    b.u = *(const uint4*)(P + SL + i);
    #pragma unroll
    for (int e = 0; e < 8; ++e) {
        float s = __bfloat162float(a.h[e]) + __bfloat162float(b.h[e]);
        r.h[e] = __float2bfloat16(s * linv);
    }
    *(uint4*)(O + i) = r.u;
}

// ---------------------------------------------------------------- launcher
extern "C" void kernel_launch(void* const* d_in, const int* in_sizes, int n_in,
                              void* d_out, int out_size, void* d_ws, size_t ws_size,
                              hipStream_t stream) {
    const float* x     = (const float*)d_in[0];
    const float* gamma = (const float*)d_in[1];
    const float* beta  = (const float*)d_in[2];
    const float* wq = (const float*)d_in[3];  const float* bq = (const float*)d_in[4];
    const float* wk = (const float*)d_in[5];  const float* bk = (const float*)d_in[6];
    const float* wv = (const float*)d_in[7];  const float* bv = (const float*)d_in[8];
    const float* wo = (const float*)d_in[9];  const float* bo = (const float*)d_in[10];
    float* out = (float*)d_out;

    // workspace layout
    char* ws = (char*)d_ws;
    float* stats = (float*)ws;  // 4 KB: 64 bg x 8 sub x {sum, sumsq}
    size_t off = 8192;
    float* lsum = (float*)(ws + off); off += (size_t)NB * Nsp * 4 + 1024;  // 32 KB row sums
    bf16* wqkb = (bf16*)(ws + off); off += (size_t)1024 * 512 * 2;        // 1 MB  [1024][512] Q then K
    bf16* wvb  = (bf16*)(ws + off); off += (size_t)512 * 512 * 2;         // 0.5 MB
    bf16* wob  = (bf16*)(ws + off); off += (size_t)512 * 512 * 2;         // 0.5 MB
    bf16* Vm   = (bf16*)(ws + off); off += (size_t)NB * Nsp * Cdim * 2;   // 8 MB  [b][c][j]
    bf16* Ot   = (bf16*)(ws + off); off += (size_t)NB * Nsp * Cdim * 2;   // 8 MB  [b][i][c]
    bf16* Opart = (bf16*)(ws + off); off += (size_t)2 * NB * Nsp * Cdim * 2;  // 16 MB: 2 j-split slabs
    bf16* ht   = (bf16*)(ws + off); off += (size_t)NB * Nsp * Cdim * 2;   // 8 MB  [b][n][c]
    bf16* QKt  = (bf16*)(ws + off); off += (size_t)NB * Nsp * 1024 * 2;   // 16 MB [b][n][1024]

    // fused: weight cvt (0..255) + lsum zero (256) + GN partial stats (257..768, 512 blocks)
    k_cvt_all<<<769, 256, 0, stream>>>(wq, wk, wv, wo, wqkb, wvb, wob, lsum, x, stats);
    // GN apply: 1024 blocks (n0 x c0 x b), finalizes partials per block
    k_gn_apply<<<dim3(64, 8, 2), 256, 0, stream>>>(x, stats, gamma, beta, ht);

    const long long hs = (long long)Nsp * Cdim;    // 2097152

    // merged QK-proj (z<2) + V-proj (z==2): 768 blocks, one launch
    k_gemm_qkv<<<dim3(32, 8, 3), 256, 0, stream>>>(ht, wqkb, wvb, bq, bk, bv, QKt, Vm);
    // fused attention: O_partial (2 j-split slabs) + lsum
    k_attn<<<dim3(64, 2, 2), 512, 0, stream>>>(QKt, Vm, lsum, Opart);
    // combine j-split partials, divide by row sums -> Ot bf16
    k_reduce2<<<2048, 256, 0, stream>>>(Opart, lsum, Ot);
    // out[co][i] = x[co][i] + bo[co] + sum_k wo[co][k] Ot[i][k]  (fp32 out + residual)
    k_gemm_nt<128, 0, 2, 1, 1, 1, 0><<<dim3(4, 32, 2), 256, 0, stream>>>(
        wob, 0, 512, Ot, hs, 512, bo, nullptr, x, hs, nullptr, out, hs, 4096, 512);
}